// Round 3
// baseline (16704.633 us; speedup 1.0000x reference)
//
#include <hip/hip_runtime.h>
#include <hip/hip_bf16.h>

#define NQq 300
#define BBb 8
#define MMm 1024
#define EEe 256
#define HHh 8
#define FFf 2048
#define LLl 6
#define RQ (NQq*BBb)   /* 2400 */
#define RM (MMm*BBb)   /* 8192 */

typedef __hip_bfloat16 bf16;
typedef unsigned short ushort_t;

__device__ __forceinline__ float b2f(bf16 v){ return __bfloat162float(v); }

// t: 0 = fp32 buffer, 1 = bf16 buffer, 2 = raw input (fp32 if f else bf16)
__device__ __forceinline__ float ld_any(const void* p, size_t i, int t, int f){
  if (t == 0) return ((const float*)p)[i];
  if (t == 1) return b2f(((const bf16*)p)[i]);
  return f ? ((const float*)p)[i] : b2f(((const bf16*)p)[i]);
}
__device__ __forceinline__ void st_any(void* p, size_t i, float v, int t){
  if (t == 0) ((float*)p)[i] = v;
  else        ((bf16*)p)[i] = __float2bfloat16(v);
}

// ---------------- dtype detector ----------------
__global__ void k_flag_init(int* flag){ if (threadIdx.x==0 && blockIdx.x==0) *flag = 0; }

// scan raw data as ushorts; bf16 inf/nan pattern (exp==0xFF) never occurs in true
// bf16 N(0,1) data but occurs ~0.4%/low-half-word if the data is fp32.
__global__ void k_detect(const ushort_t* __restrict__ p, int n, int* flag){
  int hit = 0;
  for (int i = blockIdx.x*blockDim.x + threadIdx.x; i < n; i += gridDim.x*blockDim.x){
    ushort_t u = p[i];
    if ((u & 0x7F80u) == 0x7F80u) hit = 1;
  }
  if (hit) atomicOr(flag, 1);
}

// ---------------- elementwise ----------------
__global__ void k_cvt_in(const void* __restrict__ s, float* __restrict__ d, int n,
                         const int* __restrict__ flag){
  int f = *flag;
  for (int i = blockIdx.x*blockDim.x + threadIdx.x; i < n; i += gridDim.x*blockDim.x)
    d[i] = ld_any(s, i, 2, f);
}
__global__ void k_out_dual(const float* __restrict__ s, void* __restrict__ d, int n,
                           const int* __restrict__ flag){
  int f = *flag;
  for (int i = blockIdx.x*blockDim.x + threadIdx.x; i < n; i += gridDim.x*blockDim.x){
    if (f) ((float*)d)[i] = s[i];
    else   ((bf16*)d)[i] = __float2bfloat16(s[i]);
  }
}
__global__ void k_add(const void* __restrict__ a, int at, const void* __restrict__ b, int bt,
                      void* __restrict__ y, int yt, int n, const int* __restrict__ flag){
  int f = *flag;
  for (int i = blockIdx.x*blockDim.x + threadIdx.x; i < n; i += gridDim.x*blockDim.x)
    st_any(y, i, ld_any(a,i,at,f) + ld_any(b,i,bt,f), yt);
}

// ---------------- GEMM: Y[r,o] = act( (sum_k X[r,k]*W[o,k] + b[o]) * scale ) ----------------
// W (O x K row-major) and bias are ALWAYS raw inputs (dual dtype via flag).
__global__ __launch_bounds__(256) void k_gemm(
    const void* __restrict__ X, int xt, const void* __restrict__ W,
    const void* __restrict__ bias, void* __restrict__ Y, int yt,
    int R, int K, int O, float scale, int relu, const int* __restrict__ flag)
{
  __shared__ float As[16][68];
  __shared__ float Bs[16][68];
  int f = *flag;
  int bm = blockIdx.x * 64, bn = blockIdx.y * 64;
  int tid = threadIdx.x;
  int tx = tid & 15, ty = tid >> 4;
  float acc[4][4] = {};
  for (int k0 = 0; k0 < K; k0 += 16) {
#pragma unroll
    for (int i = 0; i < 4; ++i) {
      int e = tid + i*256;          // 0..1023
      int m = e >> 4, kk = e & 15;
      int r = bm + m, k = k0 + kk;
      As[kk][m] = (r < R && k < K) ? ld_any(X, (size_t)r*K + k, xt, f) : 0.f;
      int c = bn + m;
      Bs[kk][m] = (c < O && k < K) ? ld_any(W, (size_t)c*K + k, 2, f) : 0.f;
    }
    __syncthreads();
#pragma unroll
    for (int kk = 0; kk < 16; ++kk) {
      float a0[4], b0[4];
#pragma unroll
      for (int i = 0; i < 4; ++i) a0[i] = As[kk][ty*4+i];
#pragma unroll
      for (int j = 0; j < 4; ++j) b0[j] = Bs[kk][tx*4+j];
#pragma unroll
      for (int i = 0; i < 4; ++i)
#pragma unroll
        for (int j = 0; j < 4; ++j) acc[i][j] += a0[i]*b0[j];
    }
    __syncthreads();
  }
#pragma unroll
  for (int i = 0; i < 4; ++i) {
    int r = bm + ty*4 + i;
    if (r >= R) continue;
#pragma unroll
    for (int j = 0; j < 4; ++j) {
      int c = bn + tx*4 + j;
      if (c >= O) continue;
      float v = (acc[i][j] + ld_any(bias, c, 2, f)) * scale;
      if (relu) v = fmaxf(v, 0.f);
      st_any(Y, (size_t)r*O + c, v, yt);
    }
  }
}

// ---------------- LayerNorm over E=256: Y = LN(A [+ B] [+ C]) * g + b ----------------
__device__ __forceinline__ float blk_sum256(float v, float* red){
  for (int off = 32; off; off >>= 1) v += __shfl_down(v, off, 64);
  int lane = threadIdx.x & 63, w = threadIdx.x >> 6;
  if (lane == 0) red[w] = v;
  __syncthreads();
  v = red[0] + red[1] + red[2] + red[3];
  __syncthreads();
  return v;
}

__global__ __launch_bounds__(256) void k_ln(
    const float* __restrict__ A, const float* __restrict__ Bp, const float* __restrict__ Cp,
    const void* __restrict__ g, const void* __restrict__ bt, float* __restrict__ Y,
    const int* __restrict__ flag)
{
  __shared__ float red[4];
  int f = *flag;
  int row = blockIdx.x, i = threadIdx.x;
  size_t idx = (size_t)row*256 + i;
  float x = A[idx];
  if (Bp) x += Bp[idx];
  if (Cp) x += Cp[idx];
  float m = blk_sum256(x, red) * (1.0f/256.0f);
  float d0 = x - m;
  float var = blk_sum256(d0*d0, red) * (1.0f/256.0f);
  float r = rsqrtf(var + 1e-5f);
  Y[idx] = d0 * r * ld_any(g, i, 2, f) + ld_any(bt, i, 2, f);
}

// ---------------- attention: one block per (q, b*8+h). Dh=32, H=8, B=8. ----------------
// Q fp32, K/V bf16 ws buffers, O bf16. Layout [(n*8+b)*256 + h*32 + d]. Scale pre-applied to Q.
__global__ __launch_bounds__(256) void k_attn(
    const float* __restrict__ QP, const bf16* __restrict__ KP, const bf16* __restrict__ VP,
    bf16* __restrict__ O, int Nk)
{
  int q = blockIdx.x;
  int b = blockIdx.y >> 3;
  int h = blockIdx.y & 7;
  __shared__ float qv[32];
  __shared__ float sc[1024];
  __shared__ float red[4];
  __shared__ float part[8][33];
  int tid = threadIdx.x;
  size_t qoff = ((size_t)q*8 + b)*256 + h*32;
  if (tid < 32) qv[tid] = QP[qoff + tid];
  __syncthreads();
  float lmax = -1e30f;
  for (int k = tid; k < Nk; k += 256) {
    const bf16* kr = KP + ((size_t)k*8 + b)*256 + h*32;
    float s = 0.f;
#pragma unroll
    for (int d = 0; d < 32; ++d) s += qv[d]*b2f(kr[d]);
    sc[k] = s;
    lmax = fmaxf(lmax, s);
  }
  for (int off = 32; off; off >>= 1) lmax = fmaxf(lmax, __shfl_down(lmax, off, 64));
  if ((tid & 63) == 0) red[tid >> 6] = lmax;
  __syncthreads();
  float mx = fmaxf(fmaxf(red[0], red[1]), fmaxf(red[2], red[3]));
  __syncthreads();
  float lsum = 0.f;
  for (int k = tid; k < Nk; k += 256) {
    float p = __expf(sc[k] - mx);
    sc[k] = p;
    lsum += p;
  }
  for (int off = 32; off; off >>= 1) lsum += __shfl_down(lsum, off, 64);
  if ((tid & 63) == 0) red[tid >> 6] = lsum;
  __syncthreads();
  float inv = 1.0f / (red[0] + red[1] + red[2] + red[3]);
  int d = tid & 31, g = tid >> 5;
  float o = 0.f;
  for (int k = g; k < Nk; k += 8)
    o += sc[k] * b2f(VP[((size_t)k*8 + b)*256 + h*32 + d]);
  part[g][d] = o;
  __syncthreads();
  if (tid < 32) {
    float s = 0.f;
#pragma unroll
    for (int gg = 0; gg < 8; ++gg) s += part[gg][tid];
    O[qoff + tid] = __float2bfloat16(s * inv);
  }
}

// ---------------- sine4: qse[row, c*64+i], c: 0=py 1=px 2=pw 3=ph ----------------
__global__ __launch_bounds__(256) void k_sine4(
    const float* __restrict__ rbs, const float* __restrict__ pt, bf16* __restrict__ qse)
{
  int row = blockIdx.x, tid = threadIdx.x;
  int c = tid >> 6, i = tid & 63;
  float v0 = rbs[row*4 + 0], v1 = rbs[row*4 + 1];
  float x = 1.f/(1.f + __expf(-v0));
  float y = 1.f/(1.f + __expf(-v1));
  int j = i >> 1;
  float dt = powf(10000.f, (float)(2*j)/64.f);
  const float s2pi = 6.283185307179586f;
  float base = (c == 0 || c == 3) ? y : x;   // py/ph use dim1, px/pw use dim0
  float a = base * s2pi / dt;
  bool even = ((i & 1) == 0);
  float p1 = even ? sinf(a) : cosf(a);
  float v = (c <= 1) ? p1 : (even ? sinf(p1) : cosf(p1));
  if (pt) v *= pt[(size_t)row*256 + tid];
  qse[(size_t)row*256 + tid] = __float2bfloat16(v);
}

// ---------------- host ----------------
extern "C" void kernel_launch(void* const* d_in, const int* in_sizes, int n_in,
                              void* d_out, int out_size, void* d_ws, size_t ws_size,
                              hipStream_t stream) {
  const void* tgt       = d_in[0];
  const void* memory    = d_in[1];
  const void* pos       = d_in[2];
  const void* query_pos = d_in[3];
  const void* box_embed = d_in[4];
  const bf16* sa_in_w   = (const bf16*)d_in[5];   // raw; element offsets only
  const bf16* sa_in_b   = (const bf16*)d_in[6];
  const bf16* sa_out_w  = (const bf16*)d_in[7];
  const bf16* sa_out_b  = (const bf16*)d_in[8];
  const bf16* ca_in_w   = (const bf16*)d_in[9];
  const bf16* ca_in_b   = (const bf16*)d_in[10];
  const bf16* ca_out_w  = (const bf16*)d_in[11];
  const bf16* ca_out_b  = (const bf16*)d_in[12];
  const void* ca_qpos_w = d_in[13];
  const void* ca_qpos_b = d_in[14];
  const bf16* ca_kpos_w = (const bf16*)d_in[15];
  const bf16* ca_kpos_b = (const bf16*)d_in[16];
  const bf16* ca_v_w    = (const bf16*)d_in[17];
  const bf16* ca_v_b    = (const bf16*)d_in[18];
  const bf16* ca_kc_w   = (const bf16*)d_in[19];
  const bf16* ca_kc_b   = (const bf16*)d_in[20];
  const bf16* ca_qs_w   = (const bf16*)d_in[21];
  const bf16* ca_qs_b   = (const bf16*)d_in[22];
  const bf16* ca_vp_w   = (const bf16*)d_in[23];
  const bf16* ca_vp_b   = (const bf16*)d_in[24];
  const bf16* lin1_w    = (const bf16*)d_in[25];
  const bf16* lin1_b    = (const bf16*)d_in[26];
  const bf16* lin2_w    = (const bf16*)d_in[27];
  const bf16* lin2_b    = (const bf16*)d_in[28];
  const bf16* lp1_w     = (const bf16*)d_in[29];
  const bf16* lp1_b     = (const bf16*)d_in[30];
  const bf16* lp2_w     = (const bf16*)d_in[31];
  const bf16* lp2_b     = (const bf16*)d_in[32];
  const bf16* norms_w   = (const bf16*)d_in[33];
  const bf16* norms_b   = (const bf16*)d_in[34];
  const void* qs_w1     = d_in[35];
  const void* qs_b1     = d_in[36];
  const void* qs_w2     = d_in[37];
  const void* qs_b2     = d_in[38];
  const void* rh_w1     = d_in[39];
  const void* rh_b1     = d_in[40];
  const void* rh_w2     = d_in[41];
  const void* rh_b2     = d_in[42];
  const bf16* bo_w1     = (const bf16*)d_in[43];
  const bf16* bo_b1     = (const bf16*)d_in[44];
  const bf16* bo_w2     = (const bf16*)d_in[45];
  const bf16* bo_b2     = (const bf16*)d_in[46];
  (void)in_sizes; (void)n_in; (void)out_size; (void)ws_size;

  // raw-offset helper: returns byte-agnostic element-offset pointer is NOT possible
  // without dtype; so weight offsets are applied inside a tiny wrapper that keeps
  // BOTH interpretations consistent: element offset off -> (bf16*)+off or (float*)+off.
  // We pass base pointer + element offset by computing both candidate pointers and
  // letting ld_any pick. Trick: pass (char*)base + off*esize(f)... not possible host-side.
  // Instead: pass base pointer and have k_gemm receive an extra element offset.
  // Simpler: since ld_any indexes by element, we just pass base+off via typed arithmetic
  // for BOTH dtypes — we need a single pointer. Solution: give k_gemm W/bias as base
  // pointers PLUS element offsets.
  // => implemented below via lambda capturing offsets into the call.

  float* F = (float*)d_ws;
  size_t off = 0;
  auto allocf = [&](size_t n){ float* p = F + off; off += n; return p; };
  float* OUT  = allocf((size_t)RQ*EEe);
  float* T    = allocf((size_t)RQ*EEe);
  float* TP   = allocf((size_t)RQ*EEe);
  float* T2   = allocf((size_t)RQ*EEe);
  float* T2P  = allocf((size_t)RQ*EEe);
  float* Q1   = allocf((size_t)RQ*EEe);
  float* PTf  = allocf((size_t)RQ*EEe);
  float* RBS  = allocf((size_t)RQ*4);
  float* RTMP = allocf((size_t)RQ*4);
  int*   FLAG = (int*)allocf(4);
  bf16* G = (bf16*)(F + off);
  size_t boff = 0;
  auto allocb = [&](size_t n){ bf16* p = G + boff; boff += n; return p; };
  bf16* QSE  = allocb((size_t)RQ*EEe);
  bf16* QC   = allocb((size_t)RQ*EEe);
  bf16* AO   = allocb((size_t)RQ*EEe);
  bf16* BOH  = allocb((size_t)RQ*128);
  bf16* KP   = allocb((size_t)RM*EEe);
  bf16* VP   = allocb((size_t)RM*EEe);
  bf16* KTMP = allocb((size_t)RM*EEe);
  bf16* HID  = KP;   // RQ*FFf = 4,915,200 bf16 <= 3*RM*EEe = 6,291,456 (KP,VP,part of KTMP; dead then)

  // dtype-dual raw pointer at element offset: we must NOT commit to a dtype when
  // offsetting. Both bf16*(+off) and float*(+off) differ in bytes. So all raw
  // pointers passed to kernels carry their element offset separately.
  // k_gemm above takes base W/bias; wrap calls to pre-offset via a device-safe trick:
  // we simply pass two pointers (bf16-offset and fp32-offset are same ELEMENT index
  // from the same base), i.e. pass base and use index = off + i inside ld_any calls.
  // To keep the kernel generic we fold the offset into the pointer for EACH dtype
  // identically: ld_any indexes elements from base, so base must be pre-offset.
  // => we pass base pointers un-offset and add the element offset to the index by
  // baking it into an extra arg. For simplicity we use small wrapper lambdas below
  // that pass (const void*)((const char*)0) trickery is unsafe; instead k_gemm gets
  // element offsets woff/boff2.
  auto cvt = [&](const void* s, float* d, int n){
    int blocks = (n + 255)/256; if (blocks > 2048) blocks = 2048;
    k_cvt_in<<<blocks,256,0,stream>>>(s,d,n,FLAG);
  };
  auto addk = [&](const void* a, int at, const void* b, int bt, void* y, int yt, int n){
    int blocks = (n + 255)/256; if (blocks > 2048) blocks = 2048;
    k_add<<<blocks,256,0,stream>>>(a,at,b,bt,y,yt,n,FLAG);
  };
  auto ln = [&](const float* A, const float* Bp, const float* Cp, int l, int j, float* Y){
    k_ln<<<RQ,256,0,stream>>>(A,Bp,Cp,
      (const void*)(norms_w+((size_t)l*6+j)*EEe), (const void*)(norms_b+((size_t)l*6+j)*EEe),
      Y, FLAG);
  };
  const float rs = 0.17677669529663687f;   // 1/sqrt(Dh=32)

  // NOTE on raw weight offsets: norms_w etc. are offset as bf16*. If inputs turn out
  // to be fp32, a bf16-offset pointer is WRONG. Therefore ln/gemm weight pointers must
  // be offset per-dtype inside the kernel. We handle this by passing the BASE pointer
  // and element offset. Redefine gemm wrapper accordingly:
  struct GemmArgs { };
  auto gemm = [&](const void* X, int xt, const void* Wbase, size_t woffE,
                  const void* Bbase, size_t boffE, void* Y, int yt,
                  int R, int K, int O, float scale, int relu){
    dim3 g((R+63)/64, (O+63)/64);
    // pre-offset both candidate interpretations cannot share one pointer; pass offsets
    // via two extra kernel args packed into scale-free path: we use a second kernel
    // entry that adds offsets. Simplest: launch with base pointers and offsets.
    extern __global__ void k_gemm_off(const void*,int,const void*,size_t,const void*,size_t,
                                      void*,int,int,int,int,float,int,const int*);
    k_gemm_off<<<g,256,0,stream>>>(X,xt,Wbase,woffE,Bbase,boffE,Y,yt,R,K,O,scale,relu,FLAG);
  };
  // LN weights have the same problem; re-wrap:
  auto ln2 = [&](const float* A, const float* Bp, const float* Cp, int l, int j, float* Y){
    extern __global__ void k_ln_off(const float*,const float*,const float*,
                                    const void*,size_t,const void*,size_t,float*,const int*);
    size_t o1 = ((size_t)l*6+j)*EEe;
    k_ln_off<<<RQ,256,0,stream>>>(A,Bp,Cp,(const void*)d_in[33],o1,(const void*)d_in[34],o1,Y,FLAG);
  };
  (void)ln; (void)norms_w; (void)norms_b;

  // ---- dtype detection (scan `memory` as ushorts) ----
  k_flag_init<<<1,64,0,stream>>>(FLAG);
  k_detect<<<256,256,0,stream>>>((const ushort_t*)memory, 262144, FLAG);

  cvt(tgt, OUT, RQ*EEe);

  // rbs = lin(relu(lin(query_pos, rh1)), rh2)
  gemm(query_pos, 2, rh_w1, 0, rh_b1, 0, QC, 1, RQ, EEe, EEe, 1.f, 1);
  gemm(QC, 1, rh_w2, 0, rh_b2, 0, RBS, 0, RQ, EEe, 4, 1.f, 0);

  for (int l = 0; l < LLl; ++l) {
    if (l > 0) {
      gemm(OUT, 0, qs_w1, 0, qs_b1, 0, QC, 1, RQ, EEe, EEe, 1.f, 1);
      gemm(QC, 1, qs_w2, 0, qs_b2, 0, PTf, 0, RQ, EEe, EEe, 1.f, 0);
    }
    gemm(box_embed, 2, d_in[43], (size_t)l*128*4, d_in[44], (size_t)l*128, BOH, 1, RQ, 4, 128, 1.f, 1);
    gemm(BOH, 1, d_in[45], (size_t)l*4*128, d_in[46], (size_t)l*4, RTMP, 0, RQ, 128, 4, 1.f, 0);
    addk(RBS, 0, RTMP, 0, RBS, 0, RQ*4);
    k_sine4<<<RQ,256,0,stream>>>(RBS, l > 0 ? PTf : (const float*)nullptr, QSE);

    // ---- self-attention ----
    size_t sw = (size_t)l*768*EEe, sb = (size_t)l*768;
    addk(OUT, 0, query_pos, 2, QC, 1, RQ*EEe);
    gemm(QC, 1, d_in[5], sw,             d_in[6], sb,         Q1, 0, RQ, EEe, EEe, rs,  0);
    gemm(QC, 1, d_in[5], sw+EEe*EEe,     d_in[6], sb+EEe,     KP, 1, RQ, EEe, EEe, 1.f, 0);
    gemm(OUT,0, d_in[5], sw+2*EEe*EEe,   d_in[6], sb+2*EEe,   VP, 1, RQ, EEe, EEe, 1.f, 0);
    k_attn<<<dim3(NQq, BBb*HHh),256,0,stream>>>(Q1, KP, VP, AO, NQq);
    gemm(AO, 1, d_in[7], (size_t)l*EEe*EEe, d_in[8], (size_t)l*EEe, Q1, 0, RQ, EEe, EEe, 1.f, 0);
    ln2(OUT, Q1, nullptr, l, 0, T);

    // ---- cross-attention content ----
    size_t cw = (size_t)l*768*EEe, cb = (size_t)l*768;
    const void* qc; int qct;
    if (l == 0) {
      gemm(query_pos, 2, ca_qpos_w, 0, ca_qpos_b, 0, Q1, 0, RQ, EEe, EEe, 1.f, 0);
      addk(T, 0, Q1, 0, QC, 1, RQ*EEe);
      qc = QC; qct = 1;
    } else { qc = T; qct = 0; }
    if (l == 0) {
      addk(memory, 2, pos, 2, KTMP, 1, RM*EEe);
      gemm(KTMP, 1, d_in[9], cw+EEe*EEe,   d_in[10], cb+EEe,   KP, 1, RM, EEe, EEe, 1.f, 0);
      gemm(memory,2, d_in[9], cw+2*EEe*EEe, d_in[10], cb+2*EEe, VP, 1, RM, EEe, EEe, 1.f, 0);
    } else {
      gemm(memory, 2, d_in[19], (size_t)l*EEe*EEe, d_in[20], (size_t)l*EEe, KTMP, 1, RM, EEe, EEe, 1.f, 0);
      gemm(KTMP, 1, d_in[9], cw+EEe*EEe, d_in[10], cb+EEe, KP, 1, RM, EEe, EEe, 1.f, 0);
      gemm(memory, 2, d_in[17], (size_t)l*EEe*EEe, d_in[18], (size_t)l*EEe, KTMP, 1, RM, EEe, EEe, 1.f, 0);
      gemm(KTMP, 1, d_in[9], cw+2*EEe*EEe, d_in[10], cb+2*EEe, VP, 1, RM, EEe, EEe, 1.f, 0);
    }
    gemm(qc, qct, d_in[9], cw, d_in[10], cb, Q1, 0, RQ, EEe, EEe, rs, 0);
    k_attn<<<dim3(NQq, BBb*HHh),256,0,stream>>>(Q1, KP, VP, AO, MMm);
    gemm(AO, 1, d_in[11], (size_t)l*EEe*EEe, d_in[12], (size_t)l*EEe, T2, 0, RQ, EEe, EEe, 1.f, 0);

    // ---- cross-attention positional ----
    gemm(QSE, 1, d_in[21], (size_t)l*EEe*EEe, d_in[22], (size_t)l*EEe, QC, 1, RQ, EEe, EEe, 1.f, 0);
    if (l == 0) {
      gemm(pos, 2, d_in[9], cw+EEe*EEe, d_in[10], cb+EEe, KP, 1, RM, EEe, EEe, 1.f, 0);
    } else {
      gemm(pos, 2, d_in[15], (size_t)l*EEe*EEe, d_in[16], (size_t)l*EEe, KTMP, 1, RM, EEe, EEe, 1.f, 0);
      gemm(KTMP, 1, d_in[9], cw+EEe*EEe, d_in[10], cb+EEe, KP, 1, RM, EEe, EEe, 1.f, 0);
    }
    gemm(memory, 2, d_in[23], (size_t)l*EEe*EEe, d_in[24], (size_t)l*EEe, KTMP, 1, RM, EEe, EEe, 1.f, 0);
    gemm(KTMP, 1, d_in[9], cw+2*EEe*EEe, d_in[10], cb+2*EEe, VP, 1, RM, EEe, EEe, 1.f, 0);
    gemm(QC, 1, d_in[9], cw, d_in[10], cb, Q1, 0, RQ, EEe, EEe, rs, 0);
    k_attn<<<dim3(NQq, BBb*HHh),256,0,stream>>>(Q1, KP, VP, AO, MMm);
    gemm(AO, 1, d_in[11], (size_t)l*EEe*EEe, d_in[12], (size_t)l*EEe, T2P, 0, RQ, EEe, EEe, 1.f, 0);

    // ---- tp branch ----
    ln2(T, T2P, nullptr, l, 3, TP);
    gemm(TP, 0, d_in[29], (size_t)l*FFf*EEe, d_in[30], (size_t)l*FFf, HID, 1, RQ, EEe, FFf, 1.f, 1);
    gemm(HID, 1, d_in[31], (size_t)l*EEe*FFf, d_in[32], (size_t)l*EEe, Q1, 0, RQ, FFf, EEe, 1.f, 0);
    ln2(TP, Q1, nullptr, l, 4, TP);

    // ---- t branch ----
    ln2(T, T2, T2P, l, 1, T);
    gemm(T, 0, d_in[25], (size_t)l*FFf*EEe, d_in[26], (size_t)l*FFf, HID, 1, RQ, EEe, FFf, 1.f, 1);
    gemm(HID, 1, d_in[27], (size_t)l*EEe*FFf, d_in[28], (size_t)l*EEe, Q1, 0, RQ, FFf, EEe, 1.f, 0);
    ln2(T, Q1, nullptr, l, 2, T);

    // ---- out = LN(t + tp) ----
    ln2(T, TP, nullptr, l, 5, OUT);
  }

  {
    int n = RQ*EEe;
    int blocks = (n + 255)/256; if (blocks > 2048) blocks = 2048;
    k_out_dual<<<blocks,256,0,stream>>>(OUT, d_out, n, FLAG);
  }
  (void)sa_in_w;(void)sa_in_b;(void)sa_out_w;(void)sa_out_b;(void)ca_in_w;(void)ca_in_b;
  (void)ca_out_w;(void)ca_out_b;(void)ca_kpos_w;(void)ca_kpos_b;(void)ca_v_w;(void)ca_v_b;
  (void)ca_kc_w;(void)ca_kc_b;(void)ca_qs_w;(void)ca_qs_b;(void)ca_vp_w;(void)ca_vp_b;
  (void)lin1_w;(void)lin1_b;(void)lin2_w;(void)lin2_b;(void)lp1_w;(void)lp1_b;(void)lp2_w;
  (void)lp2_b;(void)qs_w1;(void)qs_b1;(void)qs_w2;(void)qs_b2;(void)rh_w1;(void)rh_b1;
  (void)rh_w2;(void)rh_b2;(void)bo_w1;(void)bo_b1;(void)bo_w2;(void)bo_b2;
}

// ---- offset-aware variants (raw pointers cannot be element-offset host-side without
// knowing the dtype; these take base + element offset and index per-dtype) ----
__global__ __launch_bounds__(256) void k_gemm_off(
    const void* __restrict__ X, int xt, const void* __restrict__ Wb, size_t woff,
    const void* __restrict__ Bb, size_t boff2, void* __restrict__ Y, int yt,
    int R, int K, int O, float scale, int relu, const int* __restrict__ flag)
{
  __shared__ float As[16][68];
  __shared__ float Bs[16][68];
  int f = *flag;
  int bm = blockIdx.x * 64, bn = blockIdx.y * 64;
  int tid = threadIdx.x;
  int tx = tid & 15, ty = tid >> 4;
  float acc[4][4] = {};
  for (int k0 = 0; k0 < K; k0 += 16) {
#pragma unroll
    for (int i = 0; i < 4; ++i) {
      int e = tid + i*256;
      int m = e >> 4, kk = e & 15;
      int r = bm + m, k = k0 + kk;
      As[kk][m] = (r < R && k < K) ? ld_any(X, (size_t)r*K + k, xt, f) : 0.f;
      int c = bn + m;
      Bs[kk][m] = (c < O && k < K) ? ld_any(Wb, woff + (size_t)c*K + k, 2, f) : 0.f;
    }
    __syncthreads();
#pragma unroll
    for (int kk = 0; kk < 16; ++kk) {
      float a0[4], b0[4];
#pragma unroll
      for (int i = 0; i < 4; ++i) a0[i] = As[kk][ty*4+i];
#pragma unroll
      for (int j = 0; j < 4; ++j) b0[j] = Bs[kk][tx*4+j];
#pragma unroll
      for (int i = 0; i < 4; ++i)
#pragma unroll
        for (int j = 0; j < 4; ++j) acc[i][j] += a0[i]*b0[j];
    }
    __syncthreads();
  }
#pragma unroll
  for (int i = 0; i < 4; ++i) {
    int r = bm + ty*4 + i;
    if (r >= R) continue;
#pragma unroll
    for (int j = 0; j < 4; ++j) {
      int c = bn + tx*4 + j;
      if (c >= O) continue;
      float v = (acc[i][j] + ld_any(Bb, boff2 + c, 2, f)) * scale;
      if (relu) v = fmaxf(v, 0.f);
      st_any(Y, (size_t)r*O + c, v, yt);
    }
  }
}

__global__ __launch_bounds__(256) void k_ln_off(
    const float* __restrict__ A, const float* __restrict__ Bp, const float* __restrict__ Cp,
    const void* __restrict__ g, size_t goff, const void* __restrict__ bt, size_t boff,
    float* __restrict__ Y, const int* __restrict__ flag)
{
  __shared__ float red[4];
  int f = *flag;
  int row = blockIdx.x, i = threadIdx.x;
  size_t idx = (size_t)row*256 + i;
  float x = A[idx];
  if (Bp) x += Bp[idx];
  if (Cp) x += Cp[idx];
  float m = blk_sum256(x, red) * (1.0f/256.0f);
  float d0 = x - m;
  float var = blk_sum256(d0*d0, red) * (1.0f/256.0f);
  float r = rsqrtf(var + 1e-5f);
  Y[idx] = d0 * r * ld_any(g, goff + i, 2, f) + ld_any(bt, boff + i, 2, f);
}

// Round 4
// 9805.704 us; speedup vs baseline: 1.7036x; 1.7036x over previous
//
#include <hip/hip_runtime.h>
#include <hip/hip_bf16.h>

#define NQq 300
#define BBb 8
#define MMm 1024
#define EEe 256
#define FFf 2048
#define LLl 6
#define RQ 2400
#define RM 8192

typedef unsigned short u16;
typedef short bf16x8 __attribute__((ext_vector_type(8)));
typedef float f32x4 __attribute__((ext_vector_type(4)));

__device__ __forceinline__ float u2f(u16 u){ return __uint_as_float(((unsigned)u)<<16); }
__device__ __forceinline__ u16 f2u(float v){
  __hip_bfloat16 h = __float2bfloat16(v);
  return *reinterpret_cast<u16*>(&h);
}
// tag: 0 fp32 buffer, 1 bf16(u16) buffer, 2 raw input (fp32 if f else bf16)
__device__ __forceinline__ float ld_any(const void* p, size_t i, int t, int f){
  if (t == 0) return ((const float*)p)[i];
  if (t == 1) return u2f(((const u16*)p)[i]);
  return f ? ((const float*)p)[i] : u2f(((const u16*)p)[i]);
}

// ---------------- dtype detection ----------------
__global__ void k_flag_init(int* flag){ if (threadIdx.x==0 && blockIdx.x==0) *flag = 0; }
__global__ void k_detect(const u16* __restrict__ p, int n, int* flag){
  int hit = 0;
  for (int i = blockIdx.x*blockDim.x + threadIdx.x; i < n; i += gridDim.x*blockDim.x){
    u16 u = p[i];
    if ((u & 0x7F80u) == 0x7F80u) hit = 1;
  }
  if (hit) atomicOr(flag, 1);
}

// ---------------- batched input -> bf16 pool conversion ----------------
struct CvtPack {
  const void* src[47];
  int n[47];
  unsigned int off[47];
  unsigned char use[47];
};
__global__ void k_cvt_all(CvtPack pk, u16* __restrict__ pool, const int* __restrict__ flag){
  int f = *flag;
  int which = blockIdx.y;
  if (!pk.use[which]) return;
  const void* s = pk.src[which];
  int n = pk.n[which];
  u16* d = pool + pk.off[which];
  if (f) {
    const float* sf = (const float*)s;
    for (int i = blockIdx.x*blockDim.x + threadIdx.x; i < n; i += gridDim.x*blockDim.x)
      d[i] = f2u(sf[i]);
  } else {
    const u16* su = (const u16*)s;
    for (int i = blockIdx.x*blockDim.x + threadIdx.x; i < n; i += gridDim.x*blockDim.x)
      d[i] = su[i];
  }
}

// ---------------- misc elementwise ----------------
__global__ void k_cvt_in(const void* __restrict__ s, float* __restrict__ d, int n,
                         const int* __restrict__ flag){
  int f = *flag;
  for (int i = blockIdx.x*blockDim.x + threadIdx.x; i < n; i += gridDim.x*blockDim.x)
    d[i] = ld_any(s, i, 2, f);
}
__global__ void k_out_dual(const float* __restrict__ s, void* __restrict__ d, int n,
                           const int* __restrict__ flag){
  int f = *flag;
  for (int i = blockIdx.x*blockDim.x + threadIdx.x; i < n; i += gridDim.x*blockDim.x){
    if (f) ((float*)d)[i] = s[i];
    else   ((u16*)d)[i] = f2u(s[i]);
  }
}
__global__ void k_add3(const void* __restrict__ a, int at, const void* __restrict__ b, int bt,
                       void* __restrict__ y, int yt, int n){
  for (int i = blockIdx.x*blockDim.x + threadIdx.x; i < n; i += gridDim.x*blockDim.x){
    float va = at ? u2f(((const u16*)a)[i]) : ((const float*)a)[i];
    float vb = bt ? u2f(((const u16*)b)[i]) : ((const float*)b)[i];
    float v = va + vb;
    if (yt) ((u16*)y)[i] = f2u(v); else ((float*)y)[i] = v;
  }
}

// ---------------- MFMA GEMM: Y[r,o] = act((sum_k X[r,k]*W[o,k] + bias[o])*scale) ----------------
// 64x64 tile, BK=32, 256 threads = 4 waves, each wave a 32x32 quadrant (2x2 MFMA 16x16x32).
// LDS row stride 40 elems (80B): 16B-aligned b128 access, 2-way bank alias (free).
__global__ __launch_bounds__(256) void k_gemm_mfma(
    const void* __restrict__ X, int xt,
    const void* __restrict__ W, size_t woff, int wt,
    const u16* __restrict__ bias, void* __restrict__ Y, int yt,
    int R, int K, int O, float scale, int relu, const int* __restrict__ flag)
{
  __shared__ __align__(16) u16 As[64*40];
  __shared__ __align__(16) u16 Bs[64*40];
  int f = *flag;
  int bm = blockIdx.x*64, bn = blockIdx.y*64;
  int t = threadIdx.x;
  int srow = t >> 2, scg = (t & 3) << 3;
  int lane = t & 63, wv = t >> 6;
  int wrow = (wv >> 1) << 5, wcol = (wv & 1) << 5;
  int quad = lane >> 4, mr = lane & 15;
  f32x4 acc00 = {0.f,0.f,0.f,0.f}, acc01 = acc00, acc10 = acc00, acc11 = acc00;
  const bool vx = (xt == 1) && ((K & 7) == 0);
  const bool vw = (wt == 1) && ((K & 7) == 0);
  for (int k0 = 0; k0 < K; k0 += 32) {
    { // stage A (X rows)
      int gr = bm + srow;
      if (vx) {
        uint4 v = {0u,0u,0u,0u};
        if (gr < R && (k0 + scg) < K)
          v = *(const uint4*)((const u16*)X + (size_t)gr*K + k0 + scg);
        *(uint4*)&As[srow*40 + scg] = v;
      } else {
        u16 tmp[8];
#pragma unroll
        for (int u = 0; u < 8; ++u){
          int kk = k0 + scg + u;
          float v = (gr < R && kk < K) ? ld_any(X, (size_t)gr*K + kk, xt, f) : 0.f;
          tmp[u] = f2u(v);
        }
        *(uint4*)&As[srow*40 + scg] = *(uint4*)tmp;
      }
    }
    { // stage B (W rows = output cols)
      int go = bn + srow;
      if (vw) {
        uint4 v = {0u,0u,0u,0u};
        if (go < O && (k0 + scg) < K)
          v = *(const uint4*)((const u16*)W + woff + (size_t)go*K + k0 + scg);
        *(uint4*)&Bs[srow*40 + scg] = v;
      } else {
        u16 tmp[8];
#pragma unroll
        for (int u = 0; u < 8; ++u){
          int kk = k0 + scg + u;
          float v = (go < O && kk < K) ? ld_any(W, woff + (size_t)go*K + kk, wt, f) : 0.f;
          tmp[u] = f2u(v);
        }
        *(uint4*)&Bs[srow*40 + scg] = *(uint4*)tmp;
      }
    }
    __syncthreads();
    bf16x8 a0 = *(const bf16x8*)&As[(wrow      + mr)*40 + quad*8];
    bf16x8 a1 = *(const bf16x8*)&As[(wrow + 16 + mr)*40 + quad*8];
    bf16x8 b0 = *(const bf16x8*)&Bs[(wcol      + mr)*40 + quad*8];
    bf16x8 b1 = *(const bf16x8*)&Bs[(wcol + 16 + mr)*40 + quad*8];
    acc00 = __builtin_amdgcn_mfma_f32_16x16x32_bf16(a0, b0, acc00, 0, 0, 0);
    acc01 = __builtin_amdgcn_mfma_f32_16x16x32_bf16(a0, b1, acc01, 0, 0, 0);
    acc10 = __builtin_amdgcn_mfma_f32_16x16x32_bf16(a1, b0, acc10, 0, 0, 0);
    acc11 = __builtin_amdgcn_mfma_f32_16x16x32_bf16(a1, b1, acc11, 0, 0, 0);
    __syncthreads();
  }
  f32x4 av[4] = {acc00, acc01, acc10, acc11};
#pragma unroll
  for (int i = 0; i < 2; ++i)
#pragma unroll
  for (int j = 0; j < 2; ++j) {
    f32x4 a = av[i*2 + j];
    int col = bn + wcol + j*16 + mr;
    if (col >= O) continue;
    float bv = u2f(bias[col]);
#pragma unroll
    for (int r = 0; r < 4; ++r) {
      int row = bm + wrow + i*16 + quad*4 + r;
      if (row >= R) continue;
      float v = (a[r] + bv) * scale;
      if (relu) v = fmaxf(v, 0.f);
      if (yt == 0) ((float*)Y)[(size_t)row*O + col] = v;
      else         ((u16*)Y)[(size_t)row*O + col] = f2u(v);
    }
  }
}

// ---------------- LayerNorm over E=256 with dual (fp32 + bf16) output ----------------
__device__ __forceinline__ float blk_sum256(float v, float* red){
  for (int off = 32; off; off >>= 1) v += __shfl_down(v, off, 64);
  int lane = threadIdx.x & 63, w = threadIdx.x >> 6;
  if (lane == 0) red[w] = v;
  __syncthreads();
  v = red[0] + red[1] + red[2] + red[3];
  __syncthreads();
  return v;
}
__global__ __launch_bounds__(256) void k_ln2(
    const float* __restrict__ A, const float* __restrict__ Bp, const float* __restrict__ Cp,
    const u16* __restrict__ g, const u16* __restrict__ b,
    float* __restrict__ Y, u16* __restrict__ Yb)
{
  __shared__ float red[4];
  int row = blockIdx.x, i = threadIdx.x;
  size_t idx = (size_t)row*256 + i;
  float x = A[idx];
  if (Bp) x += Bp[idx];
  if (Cp) x += Cp[idx];
  float m = blk_sum256(x, red) * (1.0f/256.0f);
  float d0 = x - m;
  float var = blk_sum256(d0*d0, red) * (1.0f/256.0f);
  float r = rsqrtf(var + 1e-5f);
  float o = d0 * r * u2f(g[i]) + u2f(b[i]);
  Y[idx] = o;
  if (Yb) Yb[idx] = f2u(o);
}

// ---------------- attention: one block per (q, b*8+h). Dh=32, H=8, B=8. ----------------
__global__ __launch_bounds__(256) void k_attn(
    const float* __restrict__ QP, const u16* __restrict__ KP, const u16* __restrict__ VP,
    u16* __restrict__ O, int Nk)
{
  int q = blockIdx.x;
  int b = blockIdx.y >> 3;
  int h = blockIdx.y & 7;
  __shared__ float qv[32];
  __shared__ float sc[1024];
  __shared__ float red[4];
  __shared__ float part[8][33];
  int tid = threadIdx.x;
  size_t qoff = ((size_t)q*8 + b)*256 + h*32;
  if (tid < 32) qv[tid] = QP[qoff + tid];
  __syncthreads();
  float lmax = -1e30f;
  for (int k = tid; k < Nk; k += 256) {
    const u16* kr = KP + ((size_t)k*8 + b)*256 + h*32;
    float s = 0.f;
#pragma unroll
    for (int d = 0; d < 32; ++d) s += qv[d]*u2f(kr[d]);
    sc[k] = s;
    lmax = fmaxf(lmax, s);
  }
  for (int off = 32; off; off >>= 1) lmax = fmaxf(lmax, __shfl_down(lmax, off, 64));
  if ((tid & 63) == 0) red[tid >> 6] = lmax;
  __syncthreads();
  float mx = fmaxf(fmaxf(red[0], red[1]), fmaxf(red[2], red[3]));
  __syncthreads();
  float lsum = 0.f;
  for (int k = tid; k < Nk; k += 256) {
    float p = __expf(sc[k] - mx);
    sc[k] = p;
    lsum += p;
  }
  for (int off = 32; off; off >>= 1) lsum += __shfl_down(lsum, off, 64);
  if ((tid & 63) == 0) red[tid >> 6] = lsum;
  __syncthreads();
  float inv = 1.0f / (red[0] + red[1] + red[2] + red[3]);
  int d = tid & 31, g = tid >> 5;
  float o = 0.f;
  for (int k = g; k < Nk; k += 8)
    o += sc[k] * u2f(VP[((size_t)k*8 + b)*256 + h*32 + d]);
  part[g][d] = o;
  __syncthreads();
  if (tid < 32) {
    float s = 0.f;
#pragma unroll
    for (int gg = 0; gg < 8; ++gg) s += part[gg][tid];
    O[qoff + tid] = f2u(s * inv);
  }
}

// ---------------- sine4: qse[row, c*64+i], c: 0=py 1=px 2=pw 3=ph ----------------
__global__ __launch_bounds__(256) void k_sine4(
    const float* __restrict__ rbs, const u16* __restrict__ pt, u16* __restrict__ qse)
{
  int row = blockIdx.x, tid = threadIdx.x;
  int c = tid >> 6, i = tid & 63;
  float v0 = rbs[row*4 + 0], v1 = rbs[row*4 + 1];
  float x = 1.f/(1.f + __expf(-v0));
  float y = 1.f/(1.f + __expf(-v1));
  int j = i >> 1;
  float dt = powf(10000.f, (float)(2*j)/64.f);
  const float s2pi = 6.283185307179586f;
  float base = (c == 0 || c == 3) ? y : x;
  float a = base * s2pi / dt;
  bool even = ((i & 1) == 0);
  float p1 = even ? sinf(a) : cosf(a);
  float v = (c <= 1) ? p1 : (even ? sinf(p1) : cosf(p1));
  if (pt) v *= u2f(pt[(size_t)row*256 + tid]);
  qse[(size_t)row*256 + tid] = f2u(v);
}

// ---------------- host ----------------
extern "C" void kernel_launch(void* const* d_in, const int* in_sizes, int n_in,
                              void* d_out, int out_size, void* d_ws, size_t ws_size,
                              hipStream_t stream) {
  (void)n_in; (void)out_size;

  int* FLAG = (int*)d_ws;
  float* f32p = (float*)((char*)d_ws + 16);
  size_t fo = 0;
  auto AF = [&](size_t n){ float* p = f32p + fo; fo += n; return p; };
  float* OUT = AF(614400); float* T   = AF(614400); float* TP  = AF(614400);
  float* T2  = AF(614400); float* T2P = AF(614400); float* Q1  = AF(614400);
  float* RBS = AF(9600);   float* RTMP= AF(9600);
  u16* u16p = (u16*)(f32p + fo);
  size_t uo = 0;
  auto AU = [&](size_t n){ u16* p = u16p + uo; uo += (n + 7) & ~(size_t)7; return p; };
  u16* OUTb = AU(614400); u16* Tb  = AU(614400); u16* TPb = AU(614400);
  u16* QSE  = AU(614400); u16* QC  = AU(614400); u16* AO  = AU(614400);
  u16* PT   = AU(614400); u16* BOH = AU(307200);
  u16* KP   = AU(2097152); u16* VP = AU(2097152); u16* KTMP = AU(2097152);
  u16* HID  = KP;   // RQ*FFf = 4,915,200 <= 6,291,456 (K/V/KTMP region, dead during FFNs)
  u16* POOL = u16p + uo;

  // pool plan: all 47 inputs; big FFN weights (25,27,29,31) only if ws allows
  size_t al[47], small_e = 0, big_e = 0;
  for (int i = 0; i < 47; ++i){
    al[i] = ((size_t)in_sizes[i] + 7) & ~(size_t)7;
    if (i==25 || i==27 || i==29 || i==31) big_e += al[i]; else small_e += al[i];
  }
  size_t fixed_bytes = 16 + fo*4 + uo*2;
  bool bigpool = (fixed_bytes + (small_e + big_e)*2 + 4096 <= ws_size);
  size_t poff[47]; unsigned char usep[47];
  size_t pacc = 0;
  for (int i = 0; i < 47; ++i){
    bool u = bigpool || !(i==25 || i==27 || i==29 || i==31);
    usep[i] = u ? 1 : 0;
    poff[i] = pacc;
    if (u) pacc += al[i];
  }

  auto PPTR = [&](int i, size_t off)->const u16* { return POOL + poff[i] + off; };

  // ---- dtype detect + convert everything to bf16 pool ----
  k_flag_init<<<1,64,0,stream>>>(FLAG);
  k_detect<<<256,256,0,stream>>>((const u16*)d_in[1], 262144, FLAG);
  {
    CvtPack pk;
    for (int i = 0; i < 47; ++i){ pk.src[i]=d_in[i]; pk.n[i]=in_sizes[i];
                                  pk.off[i]=(unsigned)poff[i]; pk.use[i]=usep[i]; }
    k_cvt_all<<<dim3(96,47),256,0,stream>>>(pk, POOL, FLAG);
  }
  k_cvt_in<<<1024,256,0,stream>>>(d_in[0], OUT, RQ*EEe, FLAG);   // OUT = tgt fp32

  auto G = [&](const void* X, int xt, int widx, size_t woff, const u16* bias,
               void* Y, int yt, int R, int K, int O, float sc, int relu){
    dim3 g((R+63)/64, (O+63)/64);
    const void* W; size_t wo; int wt;
    if (usep[widx]) { W = POOL + poff[widx] + woff; wo = 0; wt = 1; }
    else            { W = d_in[widx]; wo = woff; wt = 2; }
    k_gemm_mfma<<<g,256,0,stream>>>(X,xt,W,wo,wt,bias,Y,yt,R,K,O,sc,relu,FLAG);
  };
  auto ADD = [&](const void* a,int at,const void* b,int bt,void* y,int yt,int n){
    int blocks = (n + 255)/256; if (blocks > 2048) blocks = 2048;
    k_add3<<<blocks,256,0,stream>>>(a,at,b,bt,y,yt,n);
  };
  auto LN = [&](const float* A,const float* Bp,const float* Cp,int l,int j,float* Y,u16* Yb){
    size_t o1 = ((size_t)l*6 + j)*EEe;
    k_ln2<<<RQ,256,0,stream>>>(A,Bp,Cp, PPTR(33,o1), PPTR(34,o1), Y, Yb);
  };

  const float rs = 0.17677669529663687f;  // 1/sqrt(32)
  const u16* outb = PPTR(0,0);            // bf16 view of current `out` (layer 0: tgt)
  const u16* qposb = PPTR(3,0);

  // rbs = lin(relu(lin(query_pos, rh1)), rh2)
  G(qposb,1, 39,0, PPTR(40,0), QC,1, RQ,256,256, 1.f,1);
  G(QC,1,    41,0, PPTR(42,0), RBS,0, RQ,256,4, 1.f,0);

  for (int l = 0; l < LLl; ++l) {
    size_t sw = (size_t)l*768*256, sb = (size_t)l*768;
    size_t cw = sw, cb = sb;
    // pt (l>0)
    if (l > 0) {
      G(outb,1, 35,0, PPTR(36,0), QC,1, RQ,256,256, 1.f,1);
      G(QC,1,   37,0, PPTR(38,0), PT,1, RQ,256,256, 1.f,0);
    }
    // rbs += bo-MLP(box_embed)
    G(PPTR(4,0),1, 43,(size_t)l*512, PPTR(44,(size_t)l*128), BOH,1, RQ,4,128, 1.f,1);
    G(BOH,1,       45,(size_t)l*512, PPTR(46,(size_t)l*4),   RTMP,0, RQ,128,4, 1.f,0);
    ADD(RBS,0, RTMP,0, RBS,0, RQ*4);
    k_sine4<<<RQ,256,0,stream>>>(RBS, l > 0 ? PT : (const u16*)nullptr, QSE);

    // ---- self-attention: q=k=out+query_pos, v=out ----
    ADD(OUT,0, qposb,1, QC,1, RQ*EEe);
    G(QC,1,  5, sw,          PPTR(6,sb),     Q1,0, RQ,256,256, rs, 0);
    G(QC,1,  5, sw+65536,    PPTR(6,sb+256), KP,1, RQ,256,256, 1.f,0);
    G(outb,1,5, sw+131072,   PPTR(6,sb+512), VP,1, RQ,256,256, 1.f,0);
    k_attn<<<dim3(NQq,64),256,0,stream>>>(Q1, KP, VP, AO, NQq);
    G(AO,1, 7,(size_t)l*65536, PPTR(8,(size_t)l*256), Q1,0, RQ,256,256, 1.f,0);
    LN(OUT, Q1, nullptr, l,0, T, Tb);

    // ---- cross-attention content: t2 = mha(qc, kk, v) ----
    const u16* qc;
    if (l == 0) {
      G(qposb,1, 13,0, PPTR(14,0), Q1,0, RQ,256,256, 1.f,0);
      ADD(T,0, Q1,0, QC,1, RQ*EEe);
      qc = QC;
    } else qc = Tb;
    if (l == 0) {
      ADD(PPTR(1,0),1, PPTR(2,0),1, KTMP,1, RM*EEe);           // kk = memory + pos
      G(KTMP,1,     9, cw+65536,  PPTR(10,cb+256), KP,1, RM,256,256, 1.f,0);
      G(PPTR(1,0),1,9, cw+131072, PPTR(10,cb+512), VP,1, RM,256,256, 1.f,0);
    } else {
      G(PPTR(1,0),1, 19,(size_t)l*65536, PPTR(20,(size_t)l*256), KTMP,1, RM,256,256, 1.f,0);
      G(KTMP,1,       9, cw+65536,  PPTR(10,cb+256), KP,1, RM,256,256, 1.f,0);
      G(PPTR(1,0),1, 17,(size_t)l*65536, PPTR(18,(size_t)l*256), KTMP,1, RM,256,256, 1.f,0);
      G(KTMP,1,       9, cw+131072, PPTR(10,cb+512), VP,1, RM,256,256, 1.f,0);
    }
    G(qc,1, 9, cw, PPTR(10,cb), Q1,0, RQ,256,256, rs, 0);
    k_attn<<<dim3(NQq,64),256,0,stream>>>(Q1, KP, VP, AO, MMm);
    G(AO,1, 11,(size_t)l*65536, PPTR(12,(size_t)l*256), T2,0, RQ,256,256, 1.f,0);

    // ---- cross-attention positional: t2p = mha(qse_p, kpos, vpos) ----
    G(QSE,1, 21,(size_t)l*65536, PPTR(22,(size_t)l*256), QC,1, RQ,256,256, 1.f,0);
    if (l == 0) {
      G(PPTR(2,0),1, 9, cw+65536, PPTR(10,cb+256), KP,1, RM,256,256, 1.f,0);
    } else {
      G(PPTR(2,0),1, 15,(size_t)l*65536, PPTR(16,(size_t)l*256), KTMP,1, RM,256,256, 1.f,0);
      G(KTMP,1,       9, cw+65536, PPTR(10,cb+256), KP,1, RM,256,256, 1.f,0);
    }
    G(PPTR(1,0),1, 23,(size_t)l*65536, PPTR(24,(size_t)l*256), KTMP,1, RM,256,256, 1.f,0);
    G(KTMP,1,       9, cw+131072, PPTR(10,cb+512), VP,1, RM,256,256, 1.f,0);
    G(QC,1,         9, cw,        PPTR(10,cb),     Q1,0, RQ,256,256, rs, 0);
    k_attn<<<dim3(NQq,64),256,0,stream>>>(Q1, KP, VP, AO, MMm);
    G(AO,1, 11,(size_t)l*65536, PPTR(12,(size_t)l*256), T2P,0, RQ,256,256, 1.f,0);

    // ---- tp branch: tp = LN(t + t2p); tp = LN(tp + FFN_p(tp)) ----
    LN(T, T2P, nullptr, l,3, TP, TPb);
    G(TPb,1, 29,(size_t)l*524288, PPTR(30,(size_t)l*2048), HID,1, RQ,256,2048, 1.f,1);
    G(HID,1, 31,(size_t)l*524288, PPTR(32,(size_t)l*256),  Q1,0, RQ,2048,256, 1.f,0);
    LN(TP, Q1, nullptr, l,4, TP, TPb);

    // ---- t branch: t = LN(t + t2 + t2p); t = LN(t + FFN(t)) ----
    LN(T, T2, T2P, l,1, T, Tb);
    G(Tb,1,  25,(size_t)l*524288, PPTR(26,(size_t)l*2048), HID,1, RQ,256,2048, 1.f,1);
    G(HID,1, 27,(size_t)l*524288, PPTR(28,(size_t)l*256),  Q1,0, RQ,2048,256, 1.f,0);
    LN(T, Q1, nullptr, l,2, T, Tb);

    // ---- out = LN(t + tp) ----
    LN(T, TP, nullptr, l,5, OUT, OUTb);
    outb = OUTb;
  }

  k_out_dual<<<1024,256,0,stream>>>(OUT, d_out, RQ*EEe, FLAG);
}

// Round 5
// 2883.820 us; speedup vs baseline: 5.7925x; 3.4002x over previous
//
#include <hip/hip_runtime.h>
#include <hip/hip_bf16.h>

#define NQq 300
#define BBb 8
#define MMm 1024
#define EEe 256
#define FFf 2048
#define LLl 6
#define RQ 2400
#define RM 8192

typedef unsigned short u16;
typedef short bf16x8 __attribute__((ext_vector_type(8)));
typedef float f32x4 __attribute__((ext_vector_type(4)));

__device__ __forceinline__ float u2f(u16 u){ return __uint_as_float(((unsigned)u)<<16); }
__device__ __forceinline__ u16 f2u(float v){
  __hip_bfloat16 h = __float2bfloat16(v);
  return *reinterpret_cast<u16*>(&h);
}
// tag: 0 fp32 buffer, 1 bf16(u16) buffer, 2 raw input (fp32 if f else bf16)
__device__ __forceinline__ float ld_any(const void* p, size_t i, int t, int f){
  if (t == 0) return ((const float*)p)[i];
  if (t == 1) return u2f(((const u16*)p)[i]);
  return f ? ((const float*)p)[i] : u2f(((const u16*)p)[i]);
}

// ---------------- dtype detection ----------------
__global__ void k_flag_init(int* flag){ if (threadIdx.x==0 && blockIdx.x==0) *flag = 0; }
__global__ void k_detect(const u16* __restrict__ p, int n, int* flag){
  int hit = 0;
  for (int i = blockIdx.x*blockDim.x + threadIdx.x; i < n; i += gridDim.x*blockDim.x){
    u16 u = p[i];
    if ((u & 0x7F80u) == 0x7F80u) hit = 1;
  }
  if (hit) atomicOr(flag, 1);
}

// ---------------- batched input -> bf16 pool conversion ----------------
struct CvtPack {
  const void* src[47];
  int n[47];
  unsigned int off[47];
  unsigned char use[47];
};
__global__ void k_cvt_all(CvtPack pk, u16* __restrict__ pool, const int* __restrict__ flag){
  int f = *flag;
  int which = blockIdx.y;
  if (!pk.use[which]) return;
  const void* s = pk.src[which];
  int n = pk.n[which];
  u16* d = pool + pk.off[which];
  if (f) {
    const float* sf = (const float*)s;
    for (int i = blockIdx.x*blockDim.x + threadIdx.x; i < n; i += gridDim.x*blockDim.x)
      d[i] = f2u(sf[i]);
  } else {
    const u16* su = (const u16*)s;
    for (int i = blockIdx.x*blockDim.x + threadIdx.x; i < n; i += gridDim.x*blockDim.x)
      d[i] = su[i];
  }
}

// ---------------- misc elementwise ----------------
__global__ void k_cvt_in(const void* __restrict__ s, float* __restrict__ d, int n,
                         const int* __restrict__ flag){
  int f = *flag;
  for (int i = blockIdx.x*blockDim.x + threadIdx.x; i < n; i += gridDim.x*blockDim.x)
    d[i] = ld_any(s, i, 2, f);
}
__global__ void k_out_dual(const float* __restrict__ s, void* __restrict__ d, int n,
                           const int* __restrict__ flag){
  int f = *flag;
  for (int i = blockIdx.x*blockDim.x + threadIdx.x; i < n; i += gridDim.x*blockDim.x){
    if (f) ((float*)d)[i] = s[i];
    else   ((u16*)d)[i] = f2u(s[i]);
  }
}
__global__ void k_add3(const void* __restrict__ a, int at, const void* __restrict__ b, int bt,
                       void* __restrict__ y, int yt, int n){
  for (int i = blockIdx.x*blockDim.x + threadIdx.x; i < n; i += gridDim.x*blockDim.x){
    float va = at ? u2f(((const u16*)a)[i]) : ((const float*)a)[i];
    float vb = bt ? u2f(((const u16*)b)[i]) : ((const float*)b)[i];
    float v = va + vb;
    if (yt) ((u16*)y)[i] = f2u(v); else ((float*)y)[i] = v;
  }
}

// ---------------- MFMA GEMM (unchanged from R4, known-good) ----------------
__global__ __launch_bounds__(256) void k_gemm_mfma(
    const void* __restrict__ X, int xt,
    const void* __restrict__ W, size_t woff, int wt,
    const u16* __restrict__ bias, void* __restrict__ Y, int yt,
    int R, int K, int O, float scale, int relu, const int* __restrict__ flag)
{
  __shared__ __align__(16) u16 As[64*40];
  __shared__ __align__(16) u16 Bs[64*40];
  int f = *flag;
  int bm = blockIdx.x*64, bn = blockIdx.y*64;
  int t = threadIdx.x;
  int srow = t >> 2, scg = (t & 3) << 3;
  int lane = t & 63, wv = t >> 6;
  int wrow = (wv >> 1) << 5, wcol = (wv & 1) << 5;
  int quad = lane >> 4, mr = lane & 15;
  f32x4 acc00 = {0.f,0.f,0.f,0.f}, acc01 = acc00, acc10 = acc00, acc11 = acc00;
  const bool vx = (xt == 1) && ((K & 7) == 0);
  const bool vw = (wt == 1) && ((K & 7) == 0);
  for (int k0 = 0; k0 < K; k0 += 32) {
    {
      int gr = bm + srow;
      if (vx) {
        uint4 v = {0u,0u,0u,0u};
        if (gr < R && (k0 + scg) < K)
          v = *(const uint4*)((const u16*)X + (size_t)gr*K + k0 + scg);
        *(uint4*)&As[srow*40 + scg] = v;
      } else {
        u16 tmp[8];
#pragma unroll
        for (int u = 0; u < 8; ++u){
          int kk = k0 + scg + u;
          float v = (gr < R && kk < K) ? ld_any(X, (size_t)gr*K + kk, xt, f) : 0.f;
          tmp[u] = f2u(v);
        }
        *(uint4*)&As[srow*40 + scg] = *(uint4*)tmp;
      }
    }
    {
      int go = bn + srow;
      if (vw) {
        uint4 v = {0u,0u,0u,0u};
        if (go < O && (k0 + scg) < K)
          v = *(const uint4*)((const u16*)W + woff + (size_t)go*K + k0 + scg);
        *(uint4*)&Bs[srow*40 + scg] = v;
      } else {
        u16 tmp[8];
#pragma unroll
        for (int u = 0; u < 8; ++u){
          int kk = k0 + scg + u;
          float v = (go < O && kk < K) ? ld_any(W, woff + (size_t)go*K + kk, wt, f) : 0.f;
          tmp[u] = f2u(v);
        }
        *(uint4*)&Bs[srow*40 + scg] = *(uint4*)tmp;
      }
    }
    __syncthreads();
    bf16x8 a0 = *(const bf16x8*)&As[(wrow      + mr)*40 + quad*8];
    bf16x8 a1 = *(const bf16x8*)&As[(wrow + 16 + mr)*40 + quad*8];
    bf16x8 b0 = *(const bf16x8*)&Bs[(wcol      + mr)*40 + quad*8];
    bf16x8 b1 = *(const bf16x8*)&Bs[(wcol + 16 + mr)*40 + quad*8];
    acc00 = __builtin_amdgcn_mfma_f32_16x16x32_bf16(a0, b0, acc00, 0, 0, 0);
    acc01 = __builtin_amdgcn_mfma_f32_16x16x32_bf16(a0, b1, acc01, 0, 0, 0);
    acc10 = __builtin_amdgcn_mfma_f32_16x16x32_bf16(a1, b0, acc10, 0, 0, 0);
    acc11 = __builtin_amdgcn_mfma_f32_16x16x32_bf16(a1, b1, acc11, 0, 0, 0);
    __syncthreads();
  }
  f32x4 av[4] = {acc00, acc01, acc10, acc11};
#pragma unroll
  for (int i = 0; i < 2; ++i)
#pragma unroll
  for (int j = 0; j < 2; ++j) {
    f32x4 a = av[i*2 + j];
    int col = bn + wcol + j*16 + mr;
    if (col >= O) continue;
    float bv = u2f(bias[col]);
#pragma unroll
    for (int r = 0; r < 4; ++r) {
      int row = bm + wrow + i*16 + quad*4 + r;
      if (row >= R) continue;
      float v = (a[r] + bv) * scale;
      if (relu) v = fmaxf(v, 0.f);
      if (yt == 0) ((float*)Y)[(size_t)row*O + col] = v;
      else         ((u16*)Y)[(size_t)row*O + col] = f2u(v);
    }
  }
}

// ---------------- LayerNorm with dual (fp32 + bf16) output ----------------
__device__ __forceinline__ float blk_sum256(float v, float* red){
  for (int off = 32; off; off >>= 1) v += __shfl_down(v, off, 64);
  int lane = threadIdx.x & 63, w = threadIdx.x >> 6;
  if (lane == 0) red[w] = v;
  __syncthreads();
  v = red[0] + red[1] + red[2] + red[3];
  __syncthreads();
  return v;
}
__global__ __launch_bounds__(256) void k_ln2(
    const float* __restrict__ A, const float* __restrict__ Bp, const float* __restrict__ Cp,
    const u16* __restrict__ g, const u16* __restrict__ b,
    float* __restrict__ Y, u16* __restrict__ Yb)
{
  __shared__ float red[4];
  int row = blockIdx.x, i = threadIdx.x;
  size_t idx = (size_t)row*256 + i;
  float x = A[idx];
  if (Bp) x += Bp[idx];
  if (Cp) x += Cp[idx];
  float m = blk_sum256(x, red) * (1.0f/256.0f);
  float d0 = x - m;
  float var = blk_sum256(d0*d0, red) * (1.0f/256.0f);
  float r = rsqrtf(var + 1e-5f);
  float o = d0 * r * u2f(g[i]) + u2f(b[i]);
  Y[idx] = o;
  if (Yb) Yb[idx] = f2u(o);
}

// ---------------- flash attention: block per (q-tile 64, b*8+h) ----------------
// Q (scale pre-applied, bf16), K, V layout [(n*8+b)*256 + h*32 + d]. Dh=32.
__global__ __launch_bounds__(256) void k_flash(
    const u16* __restrict__ Q, const u16* __restrict__ K, const u16* __restrict__ V,
    u16* __restrict__ O, int NQr, int Nk)
{
  __shared__ __align__(16) u16 Qs[64*40];
  __shared__ __align__(16) u16 Ks[64*40];
  __shared__ __align__(16) u16 Vs[32*72];
  __shared__ __align__(16) u16 Ps[64*72];
  int t = threadIdx.x;
  int b = blockIdx.y >> 3, h = blockIdx.y & 7;
  int q0 = blockIdx.x * 64;
  int lane = t & 63, wv = t >> 6;
  int quad = lane >> 4, mr = lane & 15;
  {
    int qi = t >> 2, c8 = (t & 3) * 8;
    int qg = q0 + qi; if (qg >= NQr) qg = NQr - 1;
    const u16* src = Q + ((size_t)qg*8 + b)*256 + h*32 + c8;
    *(uint4*)&Qs[qi*40 + c8] = *(const uint4*)src;
  }
  f32x4 o0 = {0.f,0.f,0.f,0.f}, o1 = o0;
  float m_run[4], l_run[4];
#pragma unroll
  for (int r = 0; r < 4; ++r){ m_run[r] = -1e30f; l_run[r] = 0.f; }
  __syncthreads();

  for (int k0 = 0; k0 < Nk; k0 += 64) {
    { // stage K chunk + V^T chunk
      int ki = t >> 2, c8 = (t & 3)*8;
      int kg = k0 + ki;
      uint4 kv = {0u,0u,0u,0u}, vv = {0u,0u,0u,0u};
      if (kg < Nk) {
        size_t base = ((size_t)kg*8 + b)*256 + h*32 + c8;
        kv = *(const uint4*)(K + base);
        vv = *(const uint4*)(V + base);
      }
      *(uint4*)&Ks[ki*40 + c8] = kv;
      u16 tmp[8]; *(uint4*)tmp = vv;
#pragma unroll
      for (int u = 0; u < 8; ++u) Vs[(c8+u)*72 + ki] = tmp[u];
    }
    __syncthreads();
    // S = Q·K^T for this wave's 16-row strip
    bf16x8 aq = *(const bf16x8*)&Qs[(wv*16 + mr)*40 + quad*8];
    f32x4 s[4];
#pragma unroll
    for (int j = 0; j < 4; ++j) {
      bf16x8 bk = *(const bf16x8*)&Ks[(j*16 + mr)*40 + quad*8];
      f32x4 z = {0.f,0.f,0.f,0.f};
      s[j] = __builtin_amdgcn_mfma_f32_16x16x32_bf16(aq, bk, z, 0, 0, 0);
    }
    // online softmax: rows (strip) = quad*4+reg; cols = j*16+mr
    float alpha[4];
#pragma unroll
    for (int r = 0; r < 4; ++r) {
      float cm = -1e30f;
#pragma unroll
      for (int j = 0; j < 4; ++j) {
        int kg = k0 + j*16 + mr;
        cm = fmaxf(cm, (kg < Nk) ? s[j][r] : -1e30f);
      }
      for (int msk = 1; msk < 16; msk <<= 1)
        cm = fmaxf(cm, __shfl_xor(cm, msk, 64));
      float mn = fmaxf(m_run[r], cm);
      alpha[r] = __expf(m_run[r] - mn);
      m_run[r] = mn;
      float rsum = 0.f;
#pragma unroll
      for (int j = 0; j < 4; ++j) {
        int kg = k0 + j*16 + mr;
        float p = (kg < Nk) ? __expf(s[j][r] - mn) : 0.f;
        s[j][r] = p;
        rsum += p;
      }
      for (int msk = 1; msk < 16; msk <<= 1)
        rsum += __shfl_xor(rsum, msk, 64);
      l_run[r] = l_run[r]*alpha[r] + rsum;
    }
    // P -> LDS (C-layout scatter)
#pragma unroll
    for (int j = 0; j < 4; ++j)
#pragma unroll
      for (int r = 0; r < 4; ++r)
        Ps[(wv*16 + quad*4 + r)*72 + j*16 + mr] = f2u(s[j][r]);
    __syncthreads();
    // O-chunk = P_strip(16x64)·V(64x32)
    f32x4 pv0 = {0.f,0.f,0.f,0.f}, pv1 = pv0;
#pragma unroll
    for (int st = 0; st < 2; ++st) {
      bf16x8 ap  = *(const bf16x8*)&Ps[(wv*16 + mr)*72 + st*32 + quad*8];
      bf16x8 bv0 = *(const bf16x8*)&Vs[(mr)*72      + st*32 + quad*8];
      bf16x8 bv1 = *(const bf16x8*)&Vs[(16 + mr)*72 + st*32 + quad*8];
      pv0 = __builtin_amdgcn_mfma_f32_16x16x32_bf16(ap, bv0, pv0, 0, 0, 0);
      pv1 = __builtin_amdgcn_mfma_f32_16x16x32_bf16(ap, bv1, pv1, 0, 0, 0);
    }
#pragma unroll
    for (int r = 0; r < 4; ++r) {
      o0[r] = o0[r]*alpha[r] + pv0[r];
      o1[r] = o1[r]*alpha[r] + pv1[r];
    }
    __syncthreads();
  }
#pragma unroll
  for (int r = 0; r < 4; ++r) {
    int qg = q0 + wv*16 + quad*4 + r;
    if (qg >= NQr) continue;
    float inv = 1.0f / l_run[r];
    u16* dst = O + ((size_t)qg*8 + b)*256 + h*32;
    dst[mr]      = f2u(o0[r]*inv);
    dst[16 + mr] = f2u(o1[r]*inv);
  }
}

// ---------------- sine4 ----------------
__global__ __launch_bounds__(256) void k_sine4(
    const float* __restrict__ rbs, const u16* __restrict__ pt, u16* __restrict__ qse)
{
  int row = blockIdx.x, tid = threadIdx.x;
  int c = tid >> 6, i = tid & 63;
  float v0 = rbs[row*4 + 0], v1 = rbs[row*4 + 1];
  float x = 1.f/(1.f + __expf(-v0));
  float y = 1.f/(1.f + __expf(-v1));
  int j = i >> 1;
  float dt = powf(10000.f, (float)(2*j)/64.f);
  const float s2pi = 6.283185307179586f;
  float base = (c == 0 || c == 3) ? y : x;
  float a = base * s2pi / dt;
  bool even = ((i & 1) == 0);
  float p1 = even ? sinf(a) : cosf(a);
  float v = (c <= 1) ? p1 : (even ? sinf(p1) : cosf(p1));
  if (pt) v *= u2f(pt[(size_t)row*256 + tid]);
  qse[(size_t)row*256 + tid] = f2u(v);
}

// ---------------- host ----------------
extern "C" void kernel_launch(void* const* d_in, const int* in_sizes, int n_in,
                              void* d_out, int out_size, void* d_ws, size_t ws_size,
                              hipStream_t stream) {
  (void)n_in; (void)out_size;

  int* FLAG = (int*)d_ws;
  float* f32p = (float*)((char*)d_ws + 16);
  size_t fo = 0;
  auto AF = [&](size_t n){ float* p = f32p + fo; fo += n; return p; };
  float* OUT = AF(614400); float* T   = AF(614400); float* TP  = AF(614400);
  float* T2  = AF(614400); float* T2P = AF(614400); float* Q1  = AF(614400);
  float* RBS = AF(9600);   float* RTMP= AF(9600);
  u16* u16p = (u16*)(f32p + fo);
  size_t uo = 0;
  auto AU = [&](size_t n){ u16* p = u16p + uo; uo += (n + 7) & ~(size_t)7; return p; };
  u16* OUTb = AU(614400); u16* Tb  = AU(614400); u16* TPb = AU(614400);
  u16* QSE  = AU(614400); u16* QC  = AU(614400); u16* AO  = AU(614400);
  u16* PT   = AU(614400); u16* QB  = AU(614400); u16* BOH = AU(307200);
  u16* KP   = AU(2097152); u16* VP = AU(2097152); u16* KTMP = AU(2097152);
  u16* HID  = KP;
  u16* POOL = u16p + uo;

  size_t al[47], small_e = 0, big_e = 0;
  for (int i = 0; i < 47; ++i){
    al[i] = ((size_t)in_sizes[i] + 7) & ~(size_t)7;
    if (i==25 || i==27 || i==29 || i==31) big_e += al[i]; else small_e += al[i];
  }
  size_t fixed_bytes = 16 + fo*4 + uo*2;
  bool bigpool = (fixed_bytes + (small_e + big_e)*2 + 4096 <= ws_size);
  size_t poff[47]; unsigned char usep[47];
  size_t pacc = 0;
  for (int i = 0; i < 47; ++i){
    bool u = bigpool || !(i==25 || i==27 || i==29 || i==31);
    usep[i] = u ? 1 : 0;
    poff[i] = pacc;
    if (u) pacc += al[i];
  }
  auto PPTR = [&](int i, size_t off)->const u16* { return POOL + poff[i] + off; };

  k_flag_init<<<1,64,0,stream>>>(FLAG);
  k_detect<<<256,256,0,stream>>>((const u16*)d_in[1], 262144, FLAG);
  {
    CvtPack pk;
    for (int i = 0; i < 47; ++i){ pk.src[i]=d_in[i]; pk.n[i]=in_sizes[i];
                                  pk.off[i]=(unsigned)poff[i]; pk.use[i]=usep[i]; }
    k_cvt_all<<<dim3(96,47),256,0,stream>>>(pk, POOL, FLAG);
  }
  k_cvt_in<<<1024,256,0,stream>>>(d_in[0], OUT, RQ*EEe, FLAG);

  auto G = [&](const void* X, int xt, int widx, size_t woff, const u16* bias,
               void* Y, int yt, int R, int K, int O, float sc, int relu){
    dim3 g((R+63)/64, (O+63)/64);
    const void* W; size_t wo; int wt;
    if (usep[widx]) { W = POOL + poff[widx] + woff; wo = 0; wt = 1; }
    else            { W = d_in[widx]; wo = woff; wt = 2; }
    k_gemm_mfma<<<g,256,0,stream>>>(X,xt,W,wo,wt,bias,Y,yt,R,K,O,sc,relu,FLAG);
  };
  auto ADD = [&](const void* a,int at,const void* b,int bt,void* y,int yt,int n){
    int blocks = (n + 255)/256; if (blocks > 2048) blocks = 2048;
    k_add3<<<blocks,256,0,stream>>>(a,at,b,bt,y,yt,n);
  };
  auto LN = [&](const float* A,const float* Bp,const float* Cp,int l,int j,float* Y,u16* Yb){
    size_t o1 = ((size_t)l*6 + j)*EEe;
    k_ln2<<<RQ,256,0,stream>>>(A,Bp,Cp, PPTR(33,o1), PPTR(34,o1), Y, Yb);
  };
  auto FLASH = [&](const u16* Qp, const u16* Kp, const u16* Vp, u16* Op, int Nk){
    k_flash<<<dim3(5,64),256,0,stream>>>(Qp, Kp, Vp, Op, NQq, Nk);
  };

  const float rs = 0.17677669529663687f;  // 1/sqrt(32)
  const u16* outb = PPTR(0,0);
  const u16* qposb = PPTR(3,0);

  G(qposb,1, 39,0, PPTR(40,0), QC,1, RQ,256,256, 1.f,1);
  G(QC,1,    41,0, PPTR(42,0), RBS,0, RQ,256,4, 1.f,0);

  for (int l = 0; l < LLl; ++l) {
    size_t sw = (size_t)l*768*256, sb = (size_t)l*768;
    size_t cw = sw, cb = sb;
    if (l > 0) {
      G(outb,1, 35,0, PPTR(36,0), QC,1, RQ,256,256, 1.f,1);
      G(QC,1,   37,0, PPTR(38,0), PT,1, RQ,256,256, 1.f,0);
    }
    G(PPTR(4,0),1, 43,(size_t)l*512, PPTR(44,(size_t)l*128), BOH,1, RQ,4,128, 1.f,1);
    G(BOH,1,       45,(size_t)l*512, PPTR(46,(size_t)l*4),   RTMP,0, RQ,128,4, 1.f,0);
    ADD(RBS,0, RTMP,0, RBS,0, RQ*4);
    k_sine4<<<RQ,256,0,stream>>>(RBS, l > 0 ? PT : (const u16*)nullptr, QSE);

    // ---- self-attention: q=k=out+query_pos, v=out ----
    ADD(OUT,0, qposb,1, QC,1, RQ*EEe);
    G(QC,1,  5, sw,          PPTR(6,sb),     QB,1, RQ,256,256, rs, 0);
    G(QC,1,  5, sw+65536,    PPTR(6,sb+256), KP,1, RQ,256,256, 1.f,0);
    G(outb,1,5, sw+131072,   PPTR(6,sb+512), VP,1, RQ,256,256, 1.f,0);
    FLASH(QB, KP, VP, AO, NQq);
    G(AO,1, 7,(size_t)l*65536, PPTR(8,(size_t)l*256), Q1,0, RQ,256,256, 1.f,0);
    LN(OUT, Q1, nullptr, l,0, T, Tb);

    // ---- cross-attention content ----
    const u16* qc;
    if (l == 0) {
      G(qposb,1, 13,0, PPTR(14,0), Q1,0, RQ,256,256, 1.f,0);
      ADD(T,0, Q1,0, QC,1, RQ*EEe);
      qc = QC;
    } else qc = Tb;
    if (l == 0) {
      ADD(PPTR(1,0),1, PPTR(2,0),1, KTMP,1, RM*EEe);
      G(KTMP,1,     9, cw+65536,  PPTR(10,cb+256), KP,1, RM,256,256, 1.f,0);
      G(PPTR(1,0),1,9, cw+131072, PPTR(10,cb+512), VP,1, RM,256,256, 1.f,0);
    } else {
      G(PPTR(1,0),1, 19,(size_t)l*65536, PPTR(20,(size_t)l*256), KTMP,1, RM,256,256, 1.f,0);
      G(KTMP,1,       9, cw+65536,  PPTR(10,cb+256), KP,1, RM,256,256, 1.f,0);
      G(PPTR(1,0),1, 17,(size_t)l*65536, PPTR(18,(size_t)l*256), KTMP,1, RM,256,256, 1.f,0);
      G(KTMP,1,       9, cw+131072, PPTR(10,cb+512), VP,1, RM,256,256, 1.f,0);
    }
    G(qc,1, 9, cw, PPTR(10,cb), QB,1, RQ,256,256, rs, 0);
    FLASH(QB, KP, VP, AO, MMm);
    G(AO,1, 11,(size_t)l*65536, PPTR(12,(size_t)l*256), T2,0, RQ,256,256, 1.f,0);

    // ---- cross-attention positional ----
    G(QSE,1, 21,(size_t)l*65536, PPTR(22,(size_t)l*256), QC,1, RQ,256,256, 1.f,0);
    if (l == 0) {
      G(PPTR(2,0),1, 9, cw+65536, PPTR(10,cb+256), KP,1, RM,256,256, 1.f,0);
    } else {
      G(PPTR(2,0),1, 15,(size_t)l*65536, PPTR(16,(size_t)l*256), KTMP,1, RM,256,256, 1.f,0);
      G(KTMP,1,       9, cw+65536, PPTR(10,cb+256), KP,1, RM,256,256, 1.f,0);
    }
    G(PPTR(1,0),1, 23,(size_t)l*65536, PPTR(24,(size_t)l*256), KTMP,1, RM,256,256, 1.f,0);
    G(KTMP,1,       9, cw+131072, PPTR(10,cb+512), VP,1, RM,256,256, 1.f,0);
    G(QC,1,         9, cw,        PPTR(10,cb),     QB,1, RQ,256,256, rs, 0);
    FLASH(QB, KP, VP, AO, MMm);
    G(AO,1, 11,(size_t)l*65536, PPTR(12,(size_t)l*256), T2P,0, RQ,256,256, 1.f,0);

    // ---- tp branch ----
    LN(T, T2P, nullptr, l,3, TP, TPb);
    G(TPb,1, 29,(size_t)l*524288, PPTR(30,(size_t)l*2048), HID,1, RQ,256,2048, 1.f,1);
    G(HID,1, 31,(size_t)l*524288, PPTR(32,(size_t)l*256),  Q1,0, RQ,2048,256, 1.f,0);
    LN(TP, Q1, nullptr, l,4, TP, TPb);

    // ---- t branch ----
    LN(T, T2, T2P, l,1, T, Tb);
    G(Tb,1,  25,(size_t)l*524288, PPTR(26,(size_t)l*2048), HID,1, RQ,256,2048, 1.f,1);
    G(HID,1, 27,(size_t)l*524288, PPTR(28,(size_t)l*256),  Q1,0, RQ,2048,256, 1.f,0);
    LN(T, Q1, nullptr, l,2, T, Tb);

    // ---- out = LN(t + tp) ----
    LN(T, TP, nullptr, l,5, OUT, OUTb);
    outb = OUTb;
  }

  k_out_dual<<<1024,256,0,stream>>>(OUT, d_out, RQ*EEe, FLAG);
}

// Round 6
// 2525.743 us; speedup vs baseline: 6.6137x; 1.1418x over previous
//
#include <hip/hip_runtime.h>
#include <hip/hip_bf16.h>

#define NQq 300
#define BBb 8
#define MMm 1024
#define EEe 256
#define FFf 2048
#define LLl 6
#define RQ 2400
#define RM 8192

typedef unsigned short u16;
typedef short bf16x8 __attribute__((ext_vector_type(8)));
typedef float f32x4 __attribute__((ext_vector_type(4)));

__device__ __forceinline__ float u2f(u16 u){ return __uint_as_float(((unsigned)u)<<16); }
__device__ __forceinline__ u16 f2u(float v){
  __hip_bfloat16 h = __float2bfloat16(v);
  return *reinterpret_cast<u16*>(&h);
}
__device__ __forceinline__ float ld_any(const void* p, size_t i, int t, int f){
  if (t == 0) return ((const float*)p)[i];
  if (t == 1) return u2f(((const u16*)p)[i]);
  return f ? ((const float*)p)[i] : u2f(((const u16*)p)[i]);
}

// ---------------- dtype detection ----------------
__global__ void k_flag_init(int* flag){ if (threadIdx.x==0 && blockIdx.x==0) *flag = 0; }
__global__ void k_detect(const u16* __restrict__ p, int n, int* flag){
  int hit = 0;
  for (int i = blockIdx.x*blockDim.x + threadIdx.x; i < n; i += gridDim.x*blockDim.x){
    u16 u = p[i];
    if ((u & 0x7F80u) == 0x7F80u) hit = 1;
  }
  if (hit) atomicOr(flag, 1);
}

// ---------------- batched input -> bf16 pool conversion ----------------
struct CvtPack {
  const void* src[47];
  int n[47];
  unsigned int off[47];
  unsigned char use[47];
};
__global__ void k_cvt_all(CvtPack pk, u16* __restrict__ pool, const int* __restrict__ flag){
  int f = *flag;
  int which = blockIdx.y;
  if (!pk.use[which]) return;
  const void* s = pk.src[which];
  int n = pk.n[which];
  u16* d = pool + pk.off[which];
  if (f) {
    const float* sf = (const float*)s;
    for (int i = blockIdx.x*blockDim.x + threadIdx.x; i < n; i += gridDim.x*blockDim.x)
      d[i] = f2u(sf[i]);
  } else {
    const u16* su = (const u16*)s;
    for (int i = blockIdx.x*blockDim.x + threadIdx.x; i < n; i += gridDim.x*blockDim.x)
      d[i] = su[i];
  }
}

// ---------------- misc elementwise ----------------
__global__ void k_cvt_in(const void* __restrict__ s, float* __restrict__ d, int n,
                         const int* __restrict__ flag){
  int f = *flag;
  for (int i = blockIdx.x*blockDim.x + threadIdx.x; i < n; i += gridDim.x*blockDim.x)
    d[i] = ld_any(s, i, 2, f);
}
__global__ void k_out_dual(const float* __restrict__ s, void* __restrict__ d, int n,
                           const int* __restrict__ flag){
  int f = *flag;
  for (int i = blockIdx.x*blockDim.x + threadIdx.x; i < n; i += gridDim.x*blockDim.x){
    if (f) ((float*)d)[i] = s[i];
    else   ((u16*)d)[i] = f2u(s[i]);
  }
}
__global__ void k_add3(const void* __restrict__ a, int at, const void* __restrict__ b, int bt,
                       void* __restrict__ y, int yt, int n){
  for (int i = blockIdx.x*blockDim.x + threadIdx.x; i < n; i += gridDim.x*blockDim.x){
    float va = at ? u2f(((const u16*)a)[i]) : ((const float*)a)[i];
    float vb = bt ? u2f(((const u16*)b)[i]) : ((const float*)b)[i];
    float v = va + vb;
    if (yt) ((u16*)y)[i] = f2u(v); else ((float*)y)[i] = v;
  }
}

// ---------------- weight composition: W' = A(256x256) @ B(256x256), bf16 ----------------
struct CompW { const u16* A[27]; const u16* B[27]; u16* W[27]; };
__global__ __launch_bounds__(256) void k_compose_w(CompW cw){
  int z = blockIdx.z;
  const u16* A = cw.A[z]; const u16* B = cw.B[z]; u16* Wo = cw.W[z];
  __shared__ __align__(16) u16 As[64*40];
  __shared__ __align__(16) u16 Bs[64*40];
  int bm = blockIdx.x*64, bn = blockIdx.y*64;
  int t = threadIdx.x;
  int lane = t & 63, wv = t >> 6;
  int wrow = (wv>>1)<<5, wcol = (wv&1)<<5;
  int quad = lane>>4, mr = lane&15;
  f32x4 a00 = {0.f,0.f,0.f,0.f}, a01 = a00, a10 = a00, a11 = a00;
  for (int k0 = 0; k0 < 256; k0 += 32){
    { int srow = t>>2, scg = (t&3)<<3;
      *(uint4*)&As[srow*40+scg] = *(const uint4*)(A + (size_t)(bm+srow)*256 + k0 + scg); }
    { int kk = t>>3, c8 = (t&7)<<3;
      u16 tmp[8];
      *(uint4*)tmp = *(const uint4*)(B + (size_t)(k0+kk)*256 + bn + c8);
#pragma unroll
      for (int u = 0; u < 8; ++u) Bs[(c8+u)*40 + kk] = tmp[u]; }
    __syncthreads();
    bf16x8 a0 = *(const bf16x8*)&As[(wrow+mr)*40+quad*8];
    bf16x8 a1 = *(const bf16x8*)&As[(wrow+16+mr)*40+quad*8];
    bf16x8 b0 = *(const bf16x8*)&Bs[(wcol+mr)*40+quad*8];
    bf16x8 b1 = *(const bf16x8*)&Bs[(wcol+16+mr)*40+quad*8];
    a00 = __builtin_amdgcn_mfma_f32_16x16x32_bf16(a0,b0,a00,0,0,0);
    a01 = __builtin_amdgcn_mfma_f32_16x16x32_bf16(a0,b1,a01,0,0,0);
    a10 = __builtin_amdgcn_mfma_f32_16x16x32_bf16(a1,b0,a10,0,0,0);
    a11 = __builtin_amdgcn_mfma_f32_16x16x32_bf16(a1,b1,a11,0,0,0);
    __syncthreads();
  }
  f32x4 av[4] = {a00,a01,a10,a11};
#pragma unroll
  for (int i = 0; i < 2; ++i)
#pragma unroll
  for (int j = 0; j < 2; ++j){
    f32x4 a = av[i*2+j];
    int col = bn + wcol + j*16 + mr;
#pragma unroll
    for (int r = 0; r < 4; ++r){
      int row = bm + wrow + i*16 + quad*4 + r;
      Wo[(size_t)row*256 + col] = f2u(a[r]);
    }
  }
}
struct CompB { const u16* A[27]; const u16* b1[27]; const u16* b2[27]; u16* bo[27]; };
__global__ __launch_bounds__(256) void k_compose_b(CompB cb){
  int z = blockIdx.x, o = threadIdx.x;
  const u16* A = cb.A[z];
  float acc = 0.f;
  for (int j = 0; j < 256; ++j) acc += u2f(A[(size_t)o*256 + j]) * u2f(cb.b1[z][j]);
  cb.bo[z][o] = f2u(acc + u2f(cb.b2[z][o]));
}

// ---------------- MFMA GEMM: Y[r*ldy+o] = act((sum_k X[r,k]*W[o,k] + bias[o])*scale) ----------------
__global__ __launch_bounds__(256) void k_gemm_mfma(
    const void* __restrict__ X, int xt,
    const void* __restrict__ W, size_t woff, int wt,
    const u16* __restrict__ bias, void* __restrict__ Y, int yt, int ldy,
    int R, int K, int O, float scale, int relu, const int* __restrict__ flag)
{
  __shared__ __align__(16) u16 As[64*40];
  __shared__ __align__(16) u16 Bs[64*40];
  int f = *flag;
  int bm = blockIdx.x*64, bn = blockIdx.y*64;
  int t = threadIdx.x;
  int srow = t >> 2, scg = (t & 3) << 3;
  int lane = t & 63, wv = t >> 6;
  int wrow = (wv >> 1) << 5, wcol = (wv & 1) << 5;
  int quad = lane >> 4, mr = lane & 15;
  f32x4 acc00 = {0.f,0.f,0.f,0.f}, acc01 = acc00, acc10 = acc00, acc11 = acc00;
  const bool vx = (xt == 1) && ((K & 7) == 0);
  const bool vw = (wt == 1) && ((K & 7) == 0);
  for (int k0 = 0; k0 < K; k0 += 32) {
    {
      int gr = bm + srow;
      if (vx) {
        uint4 v = {0u,0u,0u,0u};
        if (gr < R && (k0 + scg) < K)
          v = *(const uint4*)((const u16*)X + (size_t)gr*K + k0 + scg);
        *(uint4*)&As[srow*40 + scg] = v;
      } else {
        u16 tmp[8];
#pragma unroll
        for (int u = 0; u < 8; ++u){
          int kk = k0 + scg + u;
          float v = (gr < R && kk < K) ? ld_any(X, (size_t)gr*K + kk, xt, f) : 0.f;
          tmp[u] = f2u(v);
        }
        *(uint4*)&As[srow*40 + scg] = *(uint4*)tmp;
      }
    }
    {
      int go = bn + srow;
      if (vw) {
        uint4 v = {0u,0u,0u,0u};
        if (go < O && (k0 + scg) < K)
          v = *(const uint4*)((const u16*)W + woff + (size_t)go*K + k0 + scg);
        *(uint4*)&Bs[srow*40 + scg] = v;
      } else {
        u16 tmp[8];
#pragma unroll
        for (int u = 0; u < 8; ++u){
          int kk = k0 + scg + u;
          float v = (go < O && kk < K) ? ld_any(W, woff + (size_t)go*K + kk, wt, f) : 0.f;
          tmp[u] = f2u(v);
        }
        *(uint4*)&Bs[srow*40 + scg] = *(uint4*)tmp;
      }
    }
    __syncthreads();
    bf16x8 a0 = *(const bf16x8*)&As[(wrow      + mr)*40 + quad*8];
    bf16x8 a1 = *(const bf16x8*)&As[(wrow + 16 + mr)*40 + quad*8];
    bf16x8 b0 = *(const bf16x8*)&Bs[(wcol      + mr)*40 + quad*8];
    bf16x8 b1 = *(const bf16x8*)&Bs[(wcol + 16 + mr)*40 + quad*8];
    acc00 = __builtin_amdgcn_mfma_f32_16x16x32_bf16(a0, b0, acc00, 0, 0, 0);
    acc01 = __builtin_amdgcn_mfma_f32_16x16x32_bf16(a0, b1, acc01, 0, 0, 0);
    acc10 = __builtin_amdgcn_mfma_f32_16x16x32_bf16(a1, b0, acc10, 0, 0, 0);
    acc11 = __builtin_amdgcn_mfma_f32_16x16x32_bf16(a1, b1, acc11, 0, 0, 0);
    __syncthreads();
  }
  f32x4 av[4] = {acc00, acc01, acc10, acc11};
#pragma unroll
  for (int i = 0; i < 2; ++i)
#pragma unroll
  for (int j = 0; j < 2; ++j) {
    f32x4 a = av[i*2 + j];
    int col = bn + wcol + j*16 + mr;
    if (col >= O) continue;
    float bv = u2f(bias[col]);
#pragma unroll
    for (int r = 0; r < 4; ++r) {
      int row = bm + wrow + i*16 + quad*4 + r;
      if (row >= R) continue;
      float v = (a[r] + bv) * scale;
      if (relu) v = fmaxf(v, 0.f);
      if (yt == 0) ((float*)Y)[(size_t)row*ldy + col] = v;
      else         ((u16*)Y)[(size_t)row*ldy + col] = f2u(v);
    }
  }
}

// ---------------- LayerNorm with dual (fp32 + bf16) output ----------------
__device__ __forceinline__ float blk_sum256(float v, float* red){
  for (int off = 32; off; off >>= 1) v += __shfl_down(v, off, 64);
  int lane = threadIdx.x & 63, w = threadIdx.x >> 6;
  if (lane == 0) red[w] = v;
  __syncthreads();
  v = red[0] + red[1] + red[2] + red[3];
  __syncthreads();
  return v;
}
__global__ __launch_bounds__(256) void k_ln2(
    const float* __restrict__ A, const float* __restrict__ Bp, const float* __restrict__ Cp,
    const u16* __restrict__ g, const u16* __restrict__ b,
    float* __restrict__ Y, u16* __restrict__ Yb)
{
  __shared__ float red[4];
  int row = blockIdx.x, i = threadIdx.x;
  size_t idx = (size_t)row*256 + i;
  float x = A[idx];
  if (Bp) x += Bp[idx];
  if (Cp) x += Cp[idx];
  float m = blk_sum256(x, red) * (1.0f/256.0f);
  float d0 = x - m;
  float var = blk_sum256(d0*d0, red) * (1.0f/256.0f);
  float r = rsqrtf(var + 1e-5f);
  float o = d0 * r * u2f(g[i]) + u2f(b[i]);
  Y[idx] = o;
  if (Yb) Yb[idx] = f2u(o);
}

// ---------------- flash attention with per-operand row strides; scale applied to S ----------------
__global__ __launch_bounds__(256) void k_flash(
    const u16* __restrict__ Q, int qstr, const u16* __restrict__ K, int kstr,
    const u16* __restrict__ V, int vstr, u16* __restrict__ O, int NQr, int Nk, float scale)
{
  __shared__ __align__(16) u16 Qs[64*40];
  __shared__ __align__(16) u16 Ks[64*40];
  __shared__ __align__(16) u16 Vs[32*72];
  __shared__ __align__(16) u16 Ps[64*72];
  int t = threadIdx.x;
  int b = blockIdx.y >> 3, h = blockIdx.y & 7;
  int q0 = blockIdx.x * 64;
  int lane = t & 63, wv = t >> 6;
  int quad = lane >> 4, mr = lane & 15;
  {
    int qi = t >> 2, c8 = (t & 3) * 8;
    int qg = q0 + qi; if (qg >= NQr) qg = NQr - 1;
    const u16* src = Q + ((size_t)qg*8 + b)*qstr + h*32 + c8;
    *(uint4*)&Qs[qi*40 + c8] = *(const uint4*)src;
  }
  f32x4 o0 = {0.f,0.f,0.f,0.f}, o1 = o0;
  float m_run[4], l_run[4];
#pragma unroll
  for (int r = 0; r < 4; ++r){ m_run[r] = -1e30f; l_run[r] = 0.f; }
  __syncthreads();

  for (int k0 = 0; k0 < Nk; k0 += 64) {
    {
      int ki = t >> 2, c8 = (t & 3)*8;
      int kg = k0 + ki;
      uint4 kv = {0u,0u,0u,0u}, vv = {0u,0u,0u,0u};
      if (kg < Nk) {
        kv = *(const uint4*)(K + ((size_t)kg*8 + b)*kstr + h*32 + c8);
        vv = *(const uint4*)(V + ((size_t)kg*8 + b)*vstr + h*32 + c8);
      }
      *(uint4*)&Ks[ki*40 + c8] = kv;
      u16 tmp[8]; *(uint4*)tmp = vv;
#pragma unroll
      for (int u = 0; u < 8; ++u) Vs[(c8+u)*72 + ki] = tmp[u];
    }
    __syncthreads();
    bf16x8 aq = *(const bf16x8*)&Qs[(wv*16 + mr)*40 + quad*8];
    f32x4 s[4];
#pragma unroll
    for (int j = 0; j < 4; ++j) {
      bf16x8 bk = *(const bf16x8*)&Ks[(j*16 + mr)*40 + quad*8];
      f32x4 z = {0.f,0.f,0.f,0.f};
      s[j] = __builtin_amdgcn_mfma_f32_16x16x32_bf16(aq, bk, z, 0, 0, 0);
      s[j] *= scale;
    }
    float alpha[4];
#pragma unroll
    for (int r = 0; r < 4; ++r) {
      float cm = -1e30f;
#pragma unroll
      for (int j = 0; j < 4; ++j) {
        int kg = k0 + j*16 + mr;
        cm = fmaxf(cm, (kg < Nk) ? s[j][r] : -1e30f);
      }
      for (int msk = 1; msk < 16; msk <<= 1)
        cm = fmaxf(cm, __shfl_xor(cm, msk, 64));
      float mn = fmaxf(m_run[r], cm);
      alpha[r] = __expf(m_run[r] - mn);
      m_run[r] = mn;
      float rsum = 0.f;
#pragma unroll
      for (int j = 0; j < 4; ++j) {
        int kg = k0 + j*16 + mr;
        float p = (kg < Nk) ? __expf(s[j][r] - mn) : 0.f;
        s[j][r] = p;
        rsum += p;
      }
      for (int msk = 1; msk < 16; msk <<= 1)
        rsum += __shfl_xor(rsum, msk, 64);
      l_run[r] = l_run[r]*alpha[r] + rsum;
    }
#pragma unroll
    for (int j = 0; j < 4; ++j)
#pragma unroll
      for (int r = 0; r < 4; ++r)
        Ps[(wv*16 + quad*4 + r)*72 + j*16 + mr] = f2u(s[j][r]);
    __syncthreads();
    f32x4 pv0 = {0.f,0.f,0.f,0.f}, pv1 = pv0;
#pragma unroll
    for (int st = 0; st < 2; ++st) {
      bf16x8 ap  = *(const bf16x8*)&Ps[(wv*16 + mr)*72 + st*32 + quad*8];
      bf16x8 bv0 = *(const bf16x8*)&Vs[(mr)*72      + st*32 + quad*8];
      bf16x8 bv1 = *(const bf16x8*)&Vs[(16 + mr)*72 + st*32 + quad*8];
      pv0 = __builtin_amdgcn_mfma_f32_16x16x32_bf16(ap, bv0, pv0, 0, 0, 0);
      pv1 = __builtin_amdgcn_mfma_f32_16x16x32_bf16(ap, bv1, pv1, 0, 0, 0);
    }
#pragma unroll
    for (int r = 0; r < 4; ++r) {
      o0[r] = o0[r]*alpha[r] + pv0[r];
      o1[r] = o1[r]*alpha[r] + pv1[r];
    }
    __syncthreads();
  }
#pragma unroll
  for (int r = 0; r < 4; ++r) {
    int qg = q0 + wv*16 + quad*4 + r;
    if (qg >= NQr) continue;
    float inv = 1.0f / l_run[r];
    u16* dst = O + ((size_t)qg*8 + b)*256 + h*32;
    dst[mr]      = f2u(o0[r]*inv);
    dst[16 + mr] = f2u(o1[r]*inv);
  }
}

// ---------------- sine4 ----------------
__global__ __launch_bounds__(256) void k_sine4(
    const float* __restrict__ rbs, const u16* __restrict__ pt, u16* __restrict__ qse)
{
  int row = blockIdx.x, tid = threadIdx.x;
  int c = tid >> 6, i = tid & 63;
  float v0 = rbs[row*4 + 0], v1 = rbs[row*4 + 1];
  float x = 1.f/(1.f + __expf(-v0));
  float y = 1.f/(1.f + __expf(-v1));
  int j = i >> 1;
  float dt = powf(10000.f, (float)(2*j)/64.f);
  const float s2pi = 6.283185307179586f;
  float base = (c == 0 || c == 3) ? y : x;
  float a = base * s2pi / dt;
  bool even = ((i & 1) == 0);
  float p1 = even ? sinf(a) : cosf(a);
  float v = (c <= 1) ? p1 : (even ? sinf(p1) : cosf(p1));
  if (pt) v *= u2f(pt[(size_t)row*256 + tid]);
  qse[(size_t)row*256 + tid] = f2u(v);
}

// ---------------- host ----------------
extern "C" void kernel_launch(void* const* d_in, const int* in_sizes, int n_in,
                              void* d_out, int out_size, void* d_ws, size_t ws_size,
                              hipStream_t stream) {
  (void)n_in; (void)out_size;

  int* FLAG = (int*)d_ws;
  float* f32p = (float*)((char*)d_ws + 16);
  size_t fo = 0;
  auto AF = [&](size_t n){ float* p = f32p + fo; fo += n; return p; };
  float* OUT = AF(614400); float* T   = AF(614400); float* TP  = AF(614400);
  float* T2  = AF(614400); float* T2P = AF(614400); float* Q1  = AF(614400);
  float* RBS = AF(9600);   float* RTMP= AF(9600);
  u16* u16p = (u16*)(f32p + fo);
  size_t uo = 0;
  auto AU = [&](size_t n){ u16* p = u16p + uo; uo += (n + 7) & ~(size_t)7; return p; };
  u16* OUTb = AU(614400); u16* Tb  = AU(614400); u16* TPb = AU(614400);
  u16* QSE  = AU(614400); u16* QC  = AU(614400); u16* AO  = AU(614400);
  u16* PT   = AU(614400); u16* QB  = AU(614400);
  u16* QKB  = AU(1228800);           // [q|k] stacked, row stride 512
  u16* BOH  = AU(307200);
  u16* KVV  = AU((size_t)RM*768);    // [K_c|V_c|V_p], row stride 768
  u16* KPOS = AU((size_t)RM*256);    // K_pos (also SA V earlier in layer)
  u16* KTMP = AU((size_t)RM*256);    // l=0: memory+pos
  u16* HID  = KVV;                   // RQ*FFf = 4,915,200 <= RM*768 = 6,291,456
  u16* SAV  = KPOS;
  // composed weights
  u16* QPW  = AU(6*65536);  u16* QPB  = AU(6*256);
  u16* KVVW = AU(5*196608); u16* KVVB = AU(5*768);
  u16* KPW  = AU(5*65536);  u16* KPB  = AU(5*256);
  u16* VP0W = AU(65536);    u16* VP0B = AU(256);
  u16* POOL = u16p + uo;

  size_t al[47], small_e = 0, big_e = 0;
  for (int i = 0; i < 47; ++i){
    al[i] = ((size_t)in_sizes[i] + 7) & ~(size_t)7;
    if (i==25 || i==27 || i==29 || i==31) big_e += al[i]; else small_e += al[i];
  }
  size_t fixed_bytes = 16 + fo*4 + uo*2;
  bool bigpool = (fixed_bytes + (small_e + big_e)*2 + 4096 <= ws_size);
  size_t poff[47]; unsigned char usep[47];
  size_t pacc = 0;
  for (int i = 0; i < 47; ++i){
    bool u = bigpool || !(i==25 || i==27 || i==29 || i==31);
    usep[i] = u ? 1 : 0;
    poff[i] = pacc;
    if (u) pacc += al[i];
  }
  auto PPTR = [&](int i, size_t off)->const u16* { return POOL + poff[i] + off; };

  k_flag_init<<<1,64,0,stream>>>(FLAG);
  k_detect<<<256,256,0,stream>>>((const u16*)d_in[1], 262144, FLAG);
  {
    CvtPack pk;
    for (int i = 0; i < 47; ++i){ pk.src[i]=d_in[i]; pk.n[i]=in_sizes[i];
                                  pk.off[i]=(unsigned)poff[i]; pk.use[i]=usep[i]; }
    k_cvt_all<<<dim3(96,47),256,0,stream>>>(pk, POOL, FLAG);
  }
  k_cvt_in<<<1024,256,0,stream>>>(d_in[0], OUT, RQ*EEe, FLAG);

  // ---- weight compositions (27 of W'=A@B and b'=A·b1+b2) ----
  {
    CompW cw; CompB cb; int nz = 0;
    auto addc = [&](const u16* A, const u16* B, u16* W,
                    const u16* b1, const u16* b2, u16* bo){
      cw.A[nz]=A; cw.B[nz]=B; cw.W[nz]=W;
      cb.A[nz]=A; cb.b1[nz]=b1; cb.b2[nz]=b2; cb.bo[nz]=bo; ++nz;
    };
    for (int l = 0; l < 6; ++l) {
      const u16* wq = PPTR(9,(size_t)l*196608);
      addc(wq, PPTR(21,(size_t)l*65536), QPW + (size_t)l*65536,
           PPTR(22,(size_t)l*256), PPTR(10,(size_t)l*768), QPB + (size_t)l*256);
    }
    for (int l = 1; l < 6; ++l) {
      const u16* wk = PPTR(9,(size_t)l*196608 + 65536);
      const u16* wv = PPTR(9,(size_t)l*196608 + 131072);
      u16* WS = KVVW + (size_t)(l-1)*196608;
      u16* BS = KVVB + (size_t)(l-1)*768;
      addc(wk, PPTR(19,(size_t)l*65536), WS,
           PPTR(20,(size_t)l*256), PPTR(10,(size_t)l*768+256), BS);
      addc(wv, PPTR(17,(size_t)l*65536), WS + 65536,
           PPTR(18,(size_t)l*256), PPTR(10,(size_t)l*768+512), BS + 256);
      addc(wv, PPTR(23,(size_t)l*65536), WS + 131072,
           PPTR(24,(size_t)l*256), PPTR(10,(size_t)l*768+512), BS + 512);
      addc(wk, PPTR(15,(size_t)l*65536), KPW + (size_t)(l-1)*65536,
           PPTR(16,(size_t)l*256), PPTR(10,(size_t)l*768+256), KPB + (size_t)(l-1)*256);
    }
    addc(PPTR(9,131072), PPTR(23,0), VP0W, PPTR(24,0), PPTR(10,512), VP0B);
    k_compose_w<<<dim3(4,4,27),256,0,stream>>>(cw);
    k_compose_b<<<27,256,0,stream>>>(cb);
  }

  auto G = [&](const void* X, int xt, int widx, size_t woff, const u16* bias,
               void* Y, int yt, int ldy, int R, int K, int O, float sc, int relu){
    dim3 g((R+63)/64, (O+63)/64);
    const void* W; size_t wo; int wt;
    if (usep[widx]) { W = POOL + poff[widx] + woff; wo = 0; wt = 1; }
    else            { W = d_in[widx]; wo = woff; wt = 2; }
    k_gemm_mfma<<<g,256,0,stream>>>(X,xt,W,wo,wt,bias,Y,yt,ldy,R,K,O,sc,relu,FLAG);
  };
  auto GD = [&](const void* X, const u16* W, const u16* bias,
                void* Y, int yt, int ldy, int R, int K, int O){
    dim3 g((R+63)/64, (O+63)/64);
    k_gemm_mfma<<<g,256,0,stream>>>(X,1,W,0,1,bias,Y,yt,ldy,R,K,O,1.f,0,FLAG);
  };
  auto ADD = [&](const void* a,int at,const void* b,int bt,void* y,int yt,int n){
    int blocks = (n + 255)/256; if (blocks > 2048) blocks = 2048;
    k_add3<<<blocks,256,0,stream>>>(a,at,b,bt,y,yt,n);
  };
  auto LN = [&](const float* A,const float* Bp,const float* Cp,int l,int j,float* Y,u16* Yb){
    size_t o1 = ((size_t)l*6 + j)*EEe;
    k_ln2<<<RQ,256,0,stream>>>(A,Bp,Cp, PPTR(33,o1), PPTR(34,o1), Y, Yb);
  };
  const float rs = 0.17677669529663687f;  // 1/sqrt(32)
  auto FLASH = [&](const u16* Qp,int qs_,const u16* Kp,int ks_,const u16* Vp,int vs_,
                   u16* Op,int Nk){
    k_flash<<<dim3(5,64),256,0,stream>>>(Qp,qs_,Kp,ks_,Vp,vs_,Op,NQq,Nk,rs);
  };

  const u16* outb = PPTR(0,0);
  const u16* qposb = PPTR(3,0);
  const u16* memb = PPTR(1,0);
  const u16* posb = PPTR(2,0);

  G(qposb,1, 39,0, PPTR(40,0), QC,1,256, RQ,256,256, 1.f,1);
  G(QC,1,    41,0, PPTR(42,0), RBS,0,4, RQ,256,4, 1.f,0);

  for (int l = 0; l < LLl; ++l) {
    size_t sw = (size_t)l*196608, sb = (size_t)l*768;
    if (l > 0) {
      G(outb,1, 35,0, PPTR(36,0), QC,1,256, RQ,256,256, 1.f,1);
      G(QC,1,   37,0, PPTR(38,0), PT,1,256, RQ,256,256, 1.f,0);
    }
    G(PPTR(4,0),1, 43,(size_t)l*512, PPTR(44,(size_t)l*128), BOH,1,128, RQ,4,128, 1.f,1);
    G(BOH,1,       45,(size_t)l*512, PPTR(46,(size_t)l*4),   RTMP,0,4, RQ,128,4, 1.f,0);
    ADD(RBS,0, RTMP,0, RBS,0, RQ*4);
    k_sine4<<<RQ,256,0,stream>>>(RBS, l > 0 ? PT : (const u16*)nullptr, QSE);

    // ---- self-attention: [q|k] stacked from QC=out+qpos, v from out ----
    ADD(OUT,0, qposb,1, QC,1, RQ*EEe);
    G(QC,1,   5, sw,        PPTR(6,sb),     QKB,1,512, RQ,256,512, 1.f,0);
    G(outb,1, 5, sw+131072, PPTR(6,sb+512), SAV,1,256, RQ,256,256, 1.f,0);
    FLASH(QKB,512, QKB+256,512, SAV,256, AO, NQq);
    G(AO,1, 7,(size_t)l*65536, PPTR(8,(size_t)l*256), Q1,0,256, RQ,256,256, 1.f,0);
    LN(OUT, Q1, nullptr, l,0, T, Tb);

    // ---- cross-attention K/V (composed+stacked) ----
    if (l == 0) {
      ADD(memb,1, posb,1, KTMP,1, RM*EEe);
      G(KTMP,1, 9, sw+65536,  PPTR(10,sb+256), KVV,1,768,     RM,256,256, 1.f,0);
      G(memb,1, 9, sw+131072, PPTR(10,sb+512), KVV+256,1,768, RM,256,256, 1.f,0);
      GD(memb, VP0W, VP0B, KVV+512,1,768, RM,256,256);
      G(posb,1, 9, sw+65536,  PPTR(10,sb+256), KPOS,1,256,    RM,256,256, 1.f,0);
    } else {
      GD(memb, KVVW+(size_t)(l-1)*196608, KVVB+(size_t)(l-1)*768, KVV,1,768, RM,256,768);
      GD(posb, KPW+(size_t)(l-1)*65536,  KPB+(size_t)(l-1)*256,  KPOS,1,256, RM,256,256);
    }

    // ---- content attention ----
    const u16* qcb;
    if (l == 0) {
      G(qposb,1, 13,0, PPTR(14,0), Q1,0,256, RQ,256,256, 1.f,0);
      ADD(T,0, Q1,0, QC,1, RQ*EEe);
      qcb = QC;
    } else qcb = Tb;
    G(qcb,1, 9, sw, PPTR(10,sb), QB,1,256, RQ,256,256, 1.f,0);
    FLASH(QB,256, KVV,768, KVV+256,768, AO, MMm);
    G(AO,1, 11,(size_t)l*65536, PPTR(12,(size_t)l*256), T2,0,256, RQ,256,256, 1.f,0);

    // ---- positional attention (composed Q) ----
    GD(QSE, QPW+(size_t)l*65536, QPB+(size_t)l*256, QB,1,256, RQ,256,256);
    FLASH(QB,256, KPOS,256, KVV+512,768, AO, MMm);
    G(AO,1, 11,(size_t)l*65536, PPTR(12,(size_t)l*256), T2P,0,256, RQ,256,256, 1.f,0);

    // ---- tp branch ----
    LN(T, T2P, nullptr, l,3, TP, TPb);
    G(TPb,1, 29,(size_t)l*524288, PPTR(30,(size_t)l*2048), HID,1,2048, RQ,256,2048, 1.f,1);
    G(HID,1, 31,(size_t)l*524288, PPTR(32,(size_t)l*256),  Q1,0,256, RQ,2048,256, 1.f,0);
    LN(TP, Q1, nullptr, l,4, TP, TPb);

    // ---- t branch ----
    LN(T, T2, T2P, l,1, T, Tb);
    G(Tb,1,  25,(size_t)l*524288, PPTR(26,(size_t)l*2048), HID,1,2048, RQ,256,2048, 1.f,1);
    G(HID,1, 27,(size_t)l*524288, PPTR(28,(size_t)l*256),  Q1,0,256, RQ,2048,256, 1.f,0);
    LN(T, Q1, nullptr, l,2, T, Tb);

    LN(T, TP, nullptr, l,5, OUT, OUTb);
    outb = OUTb;
  }

  k_out_dual<<<1024,256,0,stream>>>(OUT, d_out, RQ*EEe, FLAG);
}

// Round 7
// 2329.174 us; speedup vs baseline: 7.1719x; 1.0844x over previous
//
#include <hip/hip_runtime.h>
#include <hip/hip_bf16.h>

#define NQq 300
#define BBb 8
#define MMm 1024
#define EEe 256
#define FFf 2048
#define LLl 6
#define RQ 2400
#define RM 8192
#define RPAD 2432   /* 38*64 */

typedef unsigned short u16;
typedef short bf16x8 __attribute__((ext_vector_type(8)));
typedef float f32x4 __attribute__((ext_vector_type(4)));

__device__ __forceinline__ float u2f(u16 u){ return __uint_as_float(((unsigned)u)<<16); }
__device__ __forceinline__ u16 f2u(float v){
  __hip_bfloat16 h = __float2bfloat16(v);
  return *reinterpret_cast<u16*>(&h);
}
// tag: 0 fp32 buffer, 1 bf16 buffer, 2 raw dual (fp32 if flag else bf16)
__device__ __forceinline__ int effdt(int t, int f){ return (t==0) ? 1 : ((t==1) ? 0 : (f?1:0)); }
__device__ __forceinline__ float ldd(const void* p, size_t i, int t, int f){
  if (t == 0) return ((const float*)p)[i];
  if (t == 1) return u2f(((const u16*)p)[i]);
  return f ? ((const float*)p)[i] : u2f(((const u16*)p)[i]);
}
// 8 contiguous elements -> floats (eoff must be %8, 16B-aligned base)
__device__ __forceinline__ void ld8f(const void* p, size_t eoff, int e, float* o){
  if (e == 0) {
    uint4 v = *(const uint4*)((const u16*)p + eoff);
    u16 tmp[8]; *(uint4*)tmp = v;
#pragma unroll
    for (int u = 0; u < 8; ++u) o[u] = u2f(tmp[u]);
  } else {
    const float* q = (const float*)p + eoff;
    float4 v0 = ((const float4*)q)[0], v1 = ((const float4*)q)[1];
    o[0]=v0.x;o[1]=v0.y;o[2]=v0.z;o[3]=v0.w;o[4]=v1.x;o[5]=v1.y;o[6]=v1.z;o[7]=v1.w;
  }
}
__device__ __forceinline__ uint4 ld8pack(const void* p, size_t eoff, int e){
  if (e == 0) return *(const uint4*)((const u16*)p + eoff);
  float o[8]; ld8f(p, eoff, 1, o);
  u16 tmp[8];
#pragma unroll
  for (int u = 0; u < 8; ++u) tmp[u] = f2u(o[u]);
  return *(uint4*)tmp;
}

// ---------------- dtype detection ----------------
__global__ void k_flag_init(int* flag){ if (threadIdx.x==0 && blockIdx.x==0) *flag = 0; }
__global__ void k_detect(const u16* __restrict__ p, int n, int* flag){
  int hit = 0;
  for (int i = blockIdx.x*blockDim.x + threadIdx.x; i < n; i += gridDim.x*blockDim.x){
    u16 u = p[i];
    if ((u & 0x7F80u) == 0x7F80u) hit = 1;
  }
  if (hit) atomicOr(flag, 1);
}

// ---------------- elementwise ----------------
__global__ void k_cvt_in(const void* __restrict__ s, float* __restrict__ d, int n,
                         const int* __restrict__ flag){
  int f = *flag;
  for (int i = blockIdx.x*blockDim.x + threadIdx.x; i < n; i += gridDim.x*blockDim.x)
    d[i] = ldd(s, i, 2, f);
}
__global__ void k_out_dual(const float* __restrict__ s, void* __restrict__ d, int n,
                           const int* __restrict__ flag){
  int f = *flag;
  for (int i = blockIdx.x*blockDim.x + threadIdx.x; i < n; i += gridDim.x*blockDim.x){
    if (f) ((float*)d)[i] = s[i];
    else   ((u16*)d)[i] = f2u(s[i]);
  }
}

// ---------------- weight composition: W' = A @ B (256x256 each), raw-dual A/B ----------------
struct CompW { const void* A[27]; size_t ao[27]; const void* B[27]; size_t bo[27]; u16* W[27]; };
__global__ __launch_bounds__(256) void k_compose_w(CompW cw, const int* __restrict__ flag){
  int f = *flag;
  int z = blockIdx.z;
  const void* A = cw.A[z]; size_t ao = cw.ao[z];
  const void* B = cw.B[z]; size_t bo = cw.bo[z];
  u16* Wo = cw.W[z];
  int ea = effdt(2,f), eb = ea;
  __shared__ __align__(16) u16 As[64*40];
  __shared__ __align__(16) u16 Bs[64*40];
  int bm = blockIdx.x*64, bn = blockIdx.y*64;
  int t = threadIdx.x;
  int lane = t & 63, wv = t >> 6;
  int wrow = (wv>>1)<<5, wcol = (wv&1)<<5;
  int quad = lane>>4, mr = lane&15;
  f32x4 a00 = {0.f,0.f,0.f,0.f}, a01 = a00, a10 = a00, a11 = a00;
  for (int k0 = 0; k0 < 256; k0 += 32){
    { int srow = t>>2, scg = (t&3)<<3;
      *(uint4*)&As[srow*40+scg] = ld8pack(A, ao + (size_t)(bm+srow)*256 + k0 + scg, ea); }
    { int kk = t>>3, c8 = (t&7)<<3;
      float o8[8]; ld8f(B, bo + (size_t)(k0+kk)*256 + bn + c8, eb, o8);
#pragma unroll
      for (int u = 0; u < 8; ++u) Bs[(c8+u)*40 + kk] = f2u(o8[u]); }
    __syncthreads();
    bf16x8 a0 = *(const bf16x8*)&As[(wrow+mr)*40+quad*8];
    bf16x8 a1 = *(const bf16x8*)&As[(wrow+16+mr)*40+quad*8];
    bf16x8 b0 = *(const bf16x8*)&Bs[(wcol+mr)*40+quad*8];
    bf16x8 b1 = *(const bf16x8*)&Bs[(wcol+16+mr)*40+quad*8];
    a00 = __builtin_amdgcn_mfma_f32_16x16x32_bf16(a0,b0,a00,0,0,0);
    a01 = __builtin_amdgcn_mfma_f32_16x16x32_bf16(a0,b1,a01,0,0,0);
    a10 = __builtin_amdgcn_mfma_f32_16x16x32_bf16(a1,b0,a10,0,0,0);
    a11 = __builtin_amdgcn_mfma_f32_16x16x32_bf16(a1,b1,a11,0,0,0);
    __syncthreads();
  }
  f32x4 av[4] = {a00,a01,a10,a11};
#pragma unroll
  for (int i = 0; i < 2; ++i)
#pragma unroll
  for (int j = 0; j < 2; ++j){
    f32x4 a = av[i*2+j];
    int col = bn + wcol + j*16 + mr;
#pragma unroll
    for (int r = 0; r < 4; ++r){
      int row = bm + wrow + i*16 + quad*4 + r;
      Wo[(size_t)row*256 + col] = f2u(a[r]);
    }
  }
}
struct CompB { const void* A[27]; size_t ao[27]; const void* b1[27]; size_t b1o[27];
               const void* b2[27]; size_t b2o[27]; u16* bo[27]; };
__global__ __launch_bounds__(256) void k_compose_b(CompB cb, const int* __restrict__ flag){
  int f = *flag;
  int z = blockIdx.x, o = threadIdx.x;
  float acc = 0.f;
  for (int j = 0; j < 256; ++j)
    acc += ldd(cb.A[z], cb.ao[z] + (size_t)o*256 + j, 2, f) * ldd(cb.b1[z], cb.b1o[z] + j, 2, f);
  cb.bo[z][o] = f2u(acc + ldd(cb.b2[z], cb.b2o[z] + o, 2, f));
}

// ---------------- generalized MFMA GEMM ----------------
// Y[r*ldy+o] = act( sum_k (X1[r,k] (+X2[r,k])) * Wsel[o,k] + biassel[o] )
// W/bias set 2 selected for row-blocks with bm >= Rsplit.
__global__ __launch_bounds__(256) void k_gemm(
    const void* __restrict__ X1, size_t xo1, int xt1,
    const void* __restrict__ X2, size_t xo2, int xt2,      // xt2 < 0 : none
    const void* __restrict__ W1, size_t wo1, int wt1,
    const void* __restrict__ B1v, size_t bo1, int bt1,
    const void* __restrict__ W2, size_t wo2, int wt2,
    const void* __restrict__ B2v, size_t bo2, int bt2,
    void* __restrict__ Y, int yt, int ldy,
    int R, int K, int O, int Rsplit, int relu, const int* __restrict__ flag)
{
  __shared__ __align__(16) u16 As[64*40];
  __shared__ __align__(16) u16 Bs[64*40];
  int f = *flag;
  int bm = blockIdx.x*64, bn = blockIdx.y*64;
  bool second = (bm >= Rsplit);
  const void* W = second ? W2 : W1;  size_t wo = second ? wo2 : wo1;  int wt = second ? wt2 : wt1;
  const void* Bv = second ? B2v : B1v; size_t bo = second ? bo2 : bo1; int bt = second ? bt2 : bt1;
  int ex1 = effdt(xt1, f), ew = effdt(wt, f);
  int t = threadIdx.x;
  int srow = t >> 2, scg = (t & 3) << 3;
  int lane = t & 63, wv = t >> 6;
  int wrow = (wv >> 1) << 5, wcol = (wv & 1) << 5;
  int quad = lane >> 4, mr = lane & 15;
  f32x4 acc00 = {0.f,0.f,0.f,0.f}, acc01 = acc00, acc10 = acc00, acc11 = acc00;
  for (int k0 = 0; k0 < K; k0 += 32) {
    { // stage X rows
      int gr = bm + srow;
      uint4 v = {0u,0u,0u,0u};
      if (gr < R) {
        size_t e = xo1 + (size_t)gr*K + k0 + scg;
        if (xt2 < 0) v = ld8pack(X1, e, ex1);
        else {
          float a8[8], b8[8];
          ld8f(X1, e, ex1, a8);
          ld8f(X2, xo2 + (size_t)gr*K + k0 + scg, effdt(xt2,f), b8);
          u16 tmp[8];
#pragma unroll
          for (int u = 0; u < 8; ++u) tmp[u] = f2u(a8[u] + b8[u]);
          v = *(uint4*)tmp;
        }
      }
      *(uint4*)&As[srow*40 + scg] = v;
    }
    { // stage W rows (output cols)
      int go = bn + srow;
      uint4 v = {0u,0u,0u,0u};
      if (go < O) v = ld8pack(W, wo + (size_t)go*K + k0 + scg, ew);
      *(uint4*)&Bs[srow*40 + scg] = v;
    }
    __syncthreads();
    bf16x8 a0 = *(const bf16x8*)&As[(wrow      + mr)*40 + quad*8];
    bf16x8 a1 = *(const bf16x8*)&As[(wrow + 16 + mr)*40 + quad*8];
    bf16x8 b0 = *(const bf16x8*)&Bs[(wcol      + mr)*40 + quad*8];
    bf16x8 b1 = *(const bf16x8*)&Bs[(wcol + 16 + mr)*40 + quad*8];
    acc00 = __builtin_amdgcn_mfma_f32_16x16x32_bf16(a0, b0, acc00, 0, 0, 0);
    acc01 = __builtin_amdgcn_mfma_f32_16x16x32_bf16(a0, b1, acc01, 0, 0, 0);
    acc10 = __builtin_amdgcn_mfma_f32_16x16x32_bf16(a1, b0, acc10, 0, 0, 0);
    acc11 = __builtin_amdgcn_mfma_f32_16x16x32_bf16(a1, b1, acc11, 0, 0, 0);
    __syncthreads();
  }
  f32x4 av[4] = {acc00, acc01, acc10, acc11};
#pragma unroll
  for (int i = 0; i < 2; ++i)
#pragma unroll
  for (int j = 0; j < 2; ++j) {
    f32x4 a = av[i*2 + j];
    int col = bn + wcol + j*16 + mr;
    if (col >= O) continue;
    float bv = ldd(Bv, bo + col, bt, f);
#pragma unroll
    for (int r = 0; r < 4; ++r) {
      int row = bm + wrow + i*16 + quad*4 + r;
      if (row >= R) continue;
      float v = a[r] + bv;
      if (relu) v = fmaxf(v, 0.f);
      if (yt == 0) ((float*)Y)[(size_t)row*ldy + col] = v;
      else         ((u16*)Y)[(size_t)row*ldy + col] = f2u(v);
    }
  }
}

// ---------------- LayerNorm (single + pair), fp32 in/out, raw-dual params ----------------
__device__ __forceinline__ float blk_sum256(float v, float* red){
  for (int off = 32; off; off >>= 1) v += __shfl_down(v, off, 64);
  int lane = threadIdx.x & 63, w = threadIdx.x >> 6;
  if (lane == 0) red[w] = v;
  __syncthreads();
  v = red[0] + red[1] + red[2] + red[3];
  __syncthreads();
  return v;
}
__device__ __forceinline__ float ln_one(float x, size_t go, size_t bo,
    const void* gb, const void* bb, int f, float* red, int i){
  float m = blk_sum256(x, red) * (1.0f/256.0f);
  float d0 = x - m;
  float var = blk_sum256(d0*d0, red) * (1.0f/256.0f);
  float r = rsqrtf(var + 1e-5f);
  return d0 * r * ldd(gb, go + i, 2, f) + ldd(bb, bo + i, 2, f);
}
__global__ __launch_bounds__(256) void k_ln(
    const float* __restrict__ A, const float* __restrict__ Bp, const float* __restrict__ Cp,
    const void* __restrict__ gb, const void* __restrict__ bb, size_t o1,
    float* __restrict__ Y, const int* __restrict__ flag)
{
  __shared__ float red[4];
  int f = *flag;
  int row = blockIdx.x, i = threadIdx.x;
  size_t idx = (size_t)row*256 + i;
  float x = A[idx];
  if (Bp) x += Bp[idx];
  if (Cp) x += Cp[idx];
  Y[idx] = ln_one(x, o1, o1, gb, bb, f, red, i);
}
__global__ __launch_bounds__(256) void k_ln_pair(
    const float* __restrict__ A1, const float* __restrict__ B1, const float* __restrict__ C1,
    size_t o1, float* __restrict__ Y1,
    const float* __restrict__ A2, const float* __restrict__ B2,
    size_t o2, float* __restrict__ Y2,
    const void* __restrict__ gb, const void* __restrict__ bb, const int* __restrict__ flag)
{
  __shared__ float red[4];
  int f = *flag;
  int row = blockIdx.x, i = threadIdx.x;
  size_t idx = (size_t)row*256 + i;
  float x1 = A1[idx] + B1[idx];
  if (C1) x1 += C1[idx];
  float x2 = A2[idx] + B2[idx];
  float y1 = ln_one(x1, o1, o1, gb, bb, f, red, i);
  float y2 = ln_one(x2, o2, o2, gb, bb, f, red, i);
  Y1[idx] = y1;
  Y2[idx] = y2;
}

// ---------------- flash attention pair (z selects problem) ----------------
struct FP {
  const u16* Q[2]; int qs[2];
  const u16* K[2]; int ks[2];
  const u16* V[2]; int vs[2];
  u16* O[2];
};
__global__ __launch_bounds__(256) void k_flash_pair(FP fp, int NQr, int Nk, float scale)
{
  __shared__ __align__(16) u16 Qs[64*40];
  __shared__ __align__(16) u16 Ks[64*40];
  __shared__ __align__(16) u16 Vs[32*72];
  __shared__ __align__(16) u16 Ps[64*72];
  int z = blockIdx.z;
  const u16* Q = fp.Q[z]; int qstr = fp.qs[z];
  const u16* K = fp.K[z]; int kstr = fp.ks[z];
  const u16* V = fp.V[z]; int vstr = fp.vs[z];
  u16* O = fp.O[z];
  int t = threadIdx.x;
  int b = blockIdx.y >> 3, h = blockIdx.y & 7;
  int q0 = blockIdx.x * 64;
  int lane = t & 63, wv = t >> 6;
  int quad = lane >> 4, mr = lane & 15;
  {
    int qi = t >> 2, c8 = (t & 3) * 8;
    int qg = q0 + qi; if (qg >= NQr) qg = NQr - 1;
    *(uint4*)&Qs[qi*40 + c8] = *(const uint4*)(Q + ((size_t)qg*8 + b)*qstr + h*32 + c8);
  }
  f32x4 o0 = {0.f,0.f,0.f,0.f}, o1 = o0;
  float m_run[4], l_run[4];
#pragma unroll
  for (int r = 0; r < 4; ++r){ m_run[r] = -1e30f; l_run[r] = 0.f; }
  __syncthreads();

  for (int k0 = 0; k0 < Nk; k0 += 64) {
    {
      int ki = t >> 2, c8 = (t & 3)*8;
      int kg = k0 + ki;
      uint4 kv = {0u,0u,0u,0u}, vv = {0u,0u,0u,0u};
      if (kg < Nk) {
        kv = *(const uint4*)(K + ((size_t)kg*8 + b)*kstr + h*32 + c8);
        vv = *(const uint4*)(V + ((size_t)kg*8 + b)*vstr + h*32 + c8);
      }
      *(uint4*)&Ks[ki*40 + c8] = kv;
      u16 tmp[8]; *(uint4*)tmp = vv;
#pragma unroll
      for (int u = 0; u < 8; ++u) Vs[(c8+u)*72 + ki] = tmp[u];
    }
    __syncthreads();
    bf16x8 aq = *(const bf16x8*)&Qs[(wv*16 + mr)*40 + quad*8];
    f32x4 s[4];
#pragma unroll
    for (int j = 0; j < 4; ++j) {
      bf16x8 bk = *(const bf16x8*)&Ks[(j*16 + mr)*40 + quad*8];
      f32x4 zz = {0.f,0.f,0.f,0.f};
      s[j] = __builtin_amdgcn_mfma_f32_16x16x32_bf16(aq, bk, zz, 0, 0, 0);
      s[j] *= scale;
    }
    float alpha[4];
#pragma unroll
    for (int r = 0; r < 4; ++r) {
      float cm = -1e30f;
#pragma unroll
      for (int j = 0; j < 4; ++j) {
        int kg = k0 + j*16 + mr;
        cm = fmaxf(cm, (kg < Nk) ? s[j][r] : -1e30f);
      }
      for (int msk = 1; msk < 16; msk <<= 1)
        cm = fmaxf(cm, __shfl_xor(cm, msk, 64));
      float mn = fmaxf(m_run[r], cm);
      alpha[r] = __expf(m_run[r] - mn);
      m_run[r] = mn;
      float rsum = 0.f;
#pragma unroll
      for (int j = 0; j < 4; ++j) {
        int kg = k0 + j*16 + mr;
        float p = (kg < Nk) ? __expf(s[j][r] - mn) : 0.f;
        s[j][r] = p;
        rsum += p;
      }
      for (int msk = 1; msk < 16; msk <<= 1)
        rsum += __shfl_xor(rsum, msk, 64);
      l_run[r] = l_run[r]*alpha[r] + rsum;
    }
#pragma unroll
    for (int j = 0; j < 4; ++j)
#pragma unroll
      for (int r = 0; r < 4; ++r)
        Ps[(wv*16 + quad*4 + r)*72 + j*16 + mr] = f2u(s[j][r]);
    __syncthreads();
    f32x4 pv0 = {0.f,0.f,0.f,0.f}, pv1 = pv0;
#pragma unroll
    for (int st = 0; st < 2; ++st) {
      bf16x8 ap  = *(const bf16x8*)&Ps[(wv*16 + mr)*72 + st*32 + quad*8];
      bf16x8 bv0 = *(const bf16x8*)&Vs[(mr)*72      + st*32 + quad*8];
      bf16x8 bv1 = *(const bf16x8*)&Vs[(16 + mr)*72 + st*32 + quad*8];
      pv0 = __builtin_amdgcn_mfma_f32_16x16x32_bf16(ap, bv0, pv0, 0, 0, 0);
      pv1 = __builtin_amdgcn_mfma_f32_16x16x32_bf16(ap, bv1, pv1, 0, 0, 0);
    }
#pragma unroll
    for (int r = 0; r < 4; ++r) {
      o0[r] = o0[r]*alpha[r] + pv0[r];
      o1[r] = o1[r]*alpha[r] + pv1[r];
    }
    __syncthreads();
  }
#pragma unroll
  for (int r = 0; r < 4; ++r) {
    int qg = q0 + wv*16 + quad*4 + r;
    if (qg >= NQr) continue;
    float inv = 1.0f / l_run[r];
    u16* dst = O + ((size_t)qg*8 + b)*256 + h*32;
    dst[mr]      = f2u(o0[r]*inv);
    dst[16 + mr] = f2u(o1[r]*inv);
  }
}

// ---------------- fused box-MLP + rbs update + sine4 ----------------
__global__ __launch_bounds__(256) void k_boxsine(
    const void* __restrict__ box, const void* __restrict__ w1, size_t w1o,
    const void* __restrict__ b1v, size_t b1o,
    const void* __restrict__ w2, size_t w2o, const void* __restrict__ b2v, size_t b2o,
    float* __restrict__ RBS, const u16* __restrict__ pt, u16* __restrict__ qse,
    const int* __restrict__ flag)
{
  int f = *flag;
  int row = blockIdx.x, t = threadIdx.x;
  __shared__ float xs[4];
  __shared__ float hs[128];
  __shared__ float rb[4];
  if (t < 4) xs[t] = ldd(box, (size_t)row*4 + t, 2, f);
  __syncthreads();
  if (t < 128) {
    float acc = ldd(b1v, b1o + t, 2, f);
#pragma unroll
    for (int j = 0; j < 4; ++j) acc += ldd(w1, w1o + (size_t)t*4 + j, 2, f) * xs[j];
    hs[t] = fmaxf(acc, 0.f);
  }
  __syncthreads();
  if (t < 4) {
    float acc = ldd(b2v, b2o + t, 2, f);
    for (int j = 0; j < 128; ++j) acc += ldd(w2, w2o + (size_t)t*128 + j, 2, f) * hs[j];
    float nr = RBS[(size_t)row*4 + t] + acc;
    RBS[(size_t)row*4 + t] = nr;
    rb[t] = nr;
  }
  __syncthreads();
  int c = t >> 6, i = t & 63;
  float x = 1.f/(1.f + __expf(-rb[0]));
  float y = 1.f/(1.f + __expf(-rb[1]));
  int j = i >> 1;
  float dt = powf(10000.f, (float)(2*j)/64.f);
  const float s2pi = 6.283185307179586f;
  float base = (c == 0 || c == 3) ? y : x;
  float a = base * s2pi / dt;
  bool even = ((i & 1) == 0);
  float p1 = even ? sinf(a) : cosf(a);
  float v = (c <= 1) ? p1 : (even ? sinf(p1) : cosf(p1));
  if (pt) v *= u2f(pt[(size_t)row*256 + t]);
  qse[(size_t)row*256 + t] = f2u(v);
}

// ---------------- host ----------------
extern "C" void kernel_launch(void* const* d_in, const int* in_sizes, int n_in,
                              void* d_out, int out_size, void* d_ws, size_t ws_size,
                              hipStream_t stream) {
  (void)in_sizes; (void)n_in; (void)out_size; (void)ws_size;

  int* FLAG = (int*)d_ws;
  float* f32p = (float*)((char*)d_ws + 16);
  size_t fo = 0;
  auto AF = [&](size_t n){ float* p = f32p + fo; fo += n; return p; };
  float* OUT = AF(614400);
  float* T   = AF((size_t)RPAD*256);   // padded; TP must follow immediately
  float* TP  = AF((size_t)RPAD*256);
  float* T2  = AF(614400);             // T2P must follow immediately
  float* T2P = AF(614400);
  float* Q1  = AF((size_t)2*RPAD*256); // stacked FFN2 output
  float* RBS = AF(9600);
  u16* u16p = (u16*)(f32p + fo);
  size_t uo = 0;
  auto AU = [&](size_t n){ u16* p = u16p + uo; uo += (n + 7) & ~(size_t)7; return p; };
  u16* QSE  = AU(614400);
  u16* QC   = AU(614400);
  u16* AO   = AU(2*614400);            // [content ; pos]
  u16* PT   = AU(614400);
  u16* QB   = AU(2*614400);            // [Q_content ; Q_pos]
  u16* QKB  = AU(1228800);             // SA [q|k], row stride 512
  u16* KVV  = AU((size_t)RM*768);      // [K_c|V_c|V_p], stride 768   (HID aliases)
  u16* KPOS = AU((size_t)RM*256);      // K_pos / SA V
  u16* KSPARE = AU((size_t)RM*256);    // extends HID span
  u16* HID  = KVV;                     // 4864*2048 = 9,961,472 <= 10,485,760
  u16* SAV  = KPOS;
  u16* QPW  = AU(6*65536);  u16* QPB  = AU(6*256);
  u16* KVVW = AU(5*196608); u16* KVVB = AU(5*768);
  u16* KPW  = AU(5*65536);  u16* KPB  = AU(5*256);
  u16* VP0W = AU(65536);    u16* VP0B = AU(256);
  (void)KSPARE;

  k_flag_init<<<1,64,0,stream>>>(FLAG);
  k_detect<<<256,256,0,stream>>>((const u16*)d_in[1], 262144, FLAG);
  k_cvt_in<<<600,256,0,stream>>>(d_in[0], OUT, RQ*EEe, FLAG);

  // ---- weight compositions (raw-dual reads) ----
  {
    CompW cw; CompB cb; int nz = 0;
    auto addc = [&](int ia, size_t ao, int ib, size_t bo_, u16* W,
                    int ib1, size_t b1o, int ib2, size_t b2o, u16* bo){
      cw.A[nz]=d_in[ia]; cw.ao[nz]=ao; cw.B[nz]=d_in[ib]; cw.bo[nz]=bo_; cw.W[nz]=W;
      cb.A[nz]=d_in[ia]; cb.ao[nz]=ao; cb.b1[nz]=d_in[ib1]; cb.b1o[nz]=b1o;
      cb.b2[nz]=d_in[ib2]; cb.b2o[nz]=b2o; cb.bo[nz]=bo; ++nz;
    };
    for (int l = 0; l < 6; ++l)
      addc(9,(size_t)l*196608, 21,(size_t)l*65536, QPW+(size_t)l*65536,
           22,(size_t)l*256, 10,(size_t)l*768, QPB+(size_t)l*256);
    for (int l = 1; l < 6; ++l) {
      size_t wk = (size_t)l*196608 + 65536, wv = (size_t)l*196608 + 131072;
      u16* WS = KVVW + (size_t)(l-1)*196608;
      u16* BS = KVVB + (size_t)(l-1)*768;
      addc(9,wk, 19,(size_t)l*65536, WS,        20,(size_t)l*256, 10,(size_t)l*768+256, BS);
      addc(9,wv, 17,(size_t)l*65536, WS+65536,  18,(size_t)l*256, 10,(size_t)l*768+512, BS+256);
      addc(9,wv, 23,(size_t)l*65536, WS+131072, 24,(size_t)l*256, 10,(size_t)l*768+512, BS+512);
      addc(9,wk, 15,(size_t)l*65536, KPW+(size_t)(l-1)*65536,
           16,(size_t)l*256, 10,(size_t)l*768+256, KPB+(size_t)(l-1)*256);
    }
    addc(9,131072, 23,0, VP0W, 24,0, 10,512, VP0B);
    k_compose_w<<<dim3(4,4,27),256,0,stream>>>(cw, FLAG);
    k_compose_b<<<27,256,0,stream>>>(cb, FLAG);
  }

  struct P { const void* p; size_t o; int t; };
  auto GEMM = [&](P X1, P X2, P W1, P B1, P W2, P B2, void* Y, int yt, int ldy,
                  int R, int K, int O, int Rsplit, int relu){
    dim3 g((R+63)/64, (O+63)/64);
    k_gemm<<<g,256,0,stream>>>(X1.p,X1.o,X1.t, X2.p,X2.o,X2.t, W1.p,W1.o,W1.t,
                               B1.p,B1.o,B1.t, W2.p,W2.o,W2.t, B2.p,B2.o,B2.t,
                               Y,yt,ldy,R,K,O,Rsplit,relu,FLAG);
  };
  P NONE = {nullptr, 0, -1};
  auto RAW = [&](int i, size_t o){ P p = {d_in[i], o, 2}; return p; };
  auto WS1 = [&](const u16* q){ P p = {q, 0, 1}; return p; };
  auto WS0 = [&](const float* q){ P p = {q, 0, 0}; return p; };
  auto G1 = [&](P X, P W, P B, void* Y, int yt, int ldy, int R, int K, int O, int relu){
    GEMM(X, NONE, W, B, W, B, Y, yt, ldy, R, K, O, R+64, relu);
  };
  auto LN1k = [&](const float* A, const float* Bp, const float* Cp, int l, int j, float* Y){
    size_t o1 = ((size_t)l*6 + j)*EEe;
    k_ln<<<RQ,256,0,stream>>>(A,Bp,Cp, d_in[33], d_in[34], o1, Y, FLAG);
  };
  const float rs = 0.17677669529663687f;  // 1/sqrt(32)

  // rbs = lin(relu(lin(query_pos, rh1)), rh2)
  G1(RAW(3,0), RAW(39,0), RAW(40,0), QC, 1, 256, RQ, 256, 256, 1);
  G1(WS1(QC),  RAW(41,0), RAW(42,0), RBS, 0, 4,  RQ, 256, 4,   0);

  for (int l = 0; l < LLl; ++l) {
    size_t sw = (size_t)l*196608, sb = (size_t)l*768;
    if (l > 0) {
      G1(WS0(OUT), RAW(35,0), RAW(36,0), QC, 1, 256, RQ, 256, 256, 1);
      G1(WS1(QC),  RAW(37,0), RAW(38,0), PT, 1, 256, RQ, 256, 256, 0);
    }
    k_boxsine<<<RQ,256,0,stream>>>(d_in[4], d_in[43],(size_t)l*512, d_in[44],(size_t)l*128,
                                   d_in[45],(size_t)l*512, d_in[46],(size_t)l*4,
                                   RBS, l > 0 ? PT : (const u16*)nullptr, QSE, FLAG);

    // ---- self-attention: [q|k] from OUT+qpos (fused add), v from OUT ----
    GEMM(WS0(OUT), RAW(3,0), RAW(5,sw), RAW(6,sb), NONE, NONE,
         QKB, 1, 512, RQ, 256, 512, RQ+64, 0);
    G1(WS0(OUT), RAW(5,sw+131072), RAW(6,sb+512), SAV, 1, 256, RQ, 256, 256, 0);
    {
      FP fp = {};
      fp.Q[0]=QKB; fp.qs[0]=512; fp.K[0]=QKB+256; fp.ks[0]=512;
      fp.V[0]=SAV; fp.vs[0]=256; fp.O[0]=AO;
      k_flash_pair<<<dim3(5,64,1),256,0,stream>>>(fp, NQq, NQq, rs);
    }
    G1(WS1(AO), RAW(7,(size_t)l*65536), RAW(8,(size_t)l*256), Q1, 0, 256, RQ, 256, 256, 0);
    LN1k(OUT, Q1, nullptr, l, 0, T);

    // ---- cross-attention K/V ----
    if (l == 0) {
      GEMM(RAW(1,0), RAW(2,0), RAW(9,sw+65536), RAW(10,sb+256), NONE, NONE,
           KVV, 1, 768, RM, 256, 256, RM+64, 0);                       // K_c = (mem+pos)@wk
      G1(RAW(1,0), RAW(9,sw+131072), RAW(10,sb+512), KVV+256, 1, 768, RM, 256, 256, 0);
      G1(RAW(1,0), WS1(VP0W), WS1(VP0B), KVV+512, 1, 768, RM, 256, 256, 0);
      G1(RAW(2,0), RAW(9,sw+65536), RAW(10,sb+256), KPOS, 1, 256, RM, 256, 256, 0);
    } else {
      G1(RAW(1,0), WS1(KVVW+(size_t)(l-1)*196608), WS1(KVVB+(size_t)(l-1)*768),
         KVV, 1, 768, RM, 256, 768, 0);
      G1(RAW(2,0), WS1(KPW+(size_t)(l-1)*65536), WS1(KPB+(size_t)(l-1)*256),
         KPOS, 1, 256, RM, 256, 256, 0);
    }

    // ---- Q projections ----
    if (l == 0) {
      G1(RAW(3,0), RAW(13,0), RAW(14,0), Q1, 0, 256, RQ, 256, 256, 0);
      GEMM(WS0(T), WS0(Q1), RAW(9,sw), RAW(10,sb), NONE, NONE,
           QB, 1, 256, RQ, 256, 256, RQ+64, 0);
    } else {
      G1(WS0(T), RAW(9,sw), RAW(10,sb), QB, 1, 256, RQ, 256, 256, 0);
    }
    G1(WS1(QSE), WS1(QPW+(size_t)l*65536), WS1(QPB+(size_t)l*256),
       QB+614400, 1, 256, RQ, 256, 256, 0);

    // ---- content + positional flash, one launch ----
    {
      FP fp = {};
      fp.Q[0]=QB;        fp.qs[0]=256; fp.K[0]=KVV;     fp.ks[0]=768;
      fp.V[0]=KVV+256;   fp.vs[0]=768; fp.O[0]=AO;
      fp.Q[1]=QB+614400; fp.qs[1]=256; fp.K[1]=KPOS;    fp.ks[1]=256;
      fp.V[1]=KVV+512;   fp.vs[1]=768; fp.O[1]=AO+614400;
      k_flash_pair<<<dim3(5,64,2),256,0,stream>>>(fp, NQq, MMm, rs);
    }
    // merged out-projection: [AO;AO2] @ ca_out_w -> [T2;T2P]
    G1(WS1(AO), RAW(11,(size_t)l*65536), RAW(12,(size_t)l*256),
       T2, 0, 256, 2*RQ, 256, 256, 0);

    // ---- LN pair #1: T=LN(T+T2+T2P,n1); TP=LN(T+T2P,n3) ----
    k_ln_pair<<<RQ,256,0,stream>>>(T, T2, T2P, ((size_t)l*6+1)*EEe, T,
                                   T, T2P, ((size_t)l*6+3)*EEe, TP,
                                   d_in[33], d_in[34], FLAG);

    // ---- merged FFNs (rows < RPAD: t-branch lin*, rows >= RPAD: tp-branch lp*) ----
    GEMM(WS0(T), NONE, RAW(25,(size_t)l*524288), RAW(26,(size_t)l*2048),
         RAW(29,(size_t)l*524288), RAW(30,(size_t)l*2048),
         HID, 1, 2048, 2*RPAD, 256, 2048, RPAD, 1);
    GEMM(WS1(HID), NONE, RAW(27,(size_t)l*524288), RAW(28,(size_t)l*256),
         RAW(31,(size_t)l*524288), RAW(32,(size_t)l*256),
         Q1, 0, 256, 2*RPAD, 2048, 256, RPAD, 0);

    // ---- LN pair #2: T=LN(T+Q1a,n2); TP=LN(TP+Q1b,n4) ----
    k_ln_pair<<<RQ,256,0,stream>>>(T, Q1, nullptr, ((size_t)l*6+2)*EEe, T,
                                   TP, Q1 + (size_t)RPAD*256, ((size_t)l*6+4)*EEe, TP,
                                   d_in[33], d_in[34], FLAG);

    // ---- out = LN(t + tp) ----
    LN1k(T, TP, nullptr, l, 5, OUT);
  }

  k_out_dual<<<600,256,0,stream>>>(OUT, d_out, RQ*EEe, FLAG);
}

// Round 8
// 2027.769 us; speedup vs baseline: 8.2379x; 1.1486x over previous
//
#include <hip/hip_runtime.h>
#include <hip/hip_bf16.h>

#define NQq 300
#define BBb 8
#define MMm 1024
#define EEe 256
#define FFf 2048
#define LLl 6
#define RQ 2400
#define RM 8192
#define RPAD 2432   /* 38*64 */

typedef unsigned short u16;
typedef short bf16x8 __attribute__((ext_vector_type(8)));
typedef float f32x4 __attribute__((ext_vector_type(4)));

__device__ __forceinline__ float u2f(u16 u){ return __uint_as_float(((unsigned)u)<<16); }
__device__ __forceinline__ u16 f2u(float v){
  __hip_bfloat16 h = __float2bfloat16(v);
  return *reinterpret_cast<u16*>(&h);
}
// tag: 0 fp32 buffer, 1 bf16 buffer, 2 raw dual (fp32 if flag else bf16)
__device__ __forceinline__ int effdt(int t, int f){ return (t==0) ? 1 : ((t==1) ? 0 : (f?1:0)); }
__device__ __forceinline__ float ldd(const void* p, size_t i, int t, int f){
  if (t == 0) return ((const float*)p)[i];
  if (t == 1) return u2f(((const u16*)p)[i]);
  return f ? ((const float*)p)[i] : u2f(((const u16*)p)[i]);
}
__device__ __forceinline__ void ld8f(const void* p, size_t eoff, int e, float* o){
  if (e == 0) {
    uint4 v = *(const uint4*)((const u16*)p + eoff);
    u16 tmp[8]; *(uint4*)tmp = v;
#pragma unroll
    for (int u = 0; u < 8; ++u) o[u] = u2f(tmp[u]);
  } else {
    const float* q = (const float*)p + eoff;
    float4 v0 = ((const float4*)q)[0], v1 = ((const float4*)q)[1];
    o[0]=v0.x;o[1]=v0.y;o[2]=v0.z;o[3]=v0.w;o[4]=v1.x;o[5]=v1.y;o[6]=v1.z;o[7]=v1.w;
  }
}
__device__ __forceinline__ uint4 ld8pack(const void* p, size_t eoff, int e){
  if (e == 0) return *(const uint4*)((const u16*)p + eoff);
  float o[8]; ld8f(p, eoff, 1, o);
  u16 tmp[8];
#pragma unroll
  for (int u = 0; u < 8; ++u) tmp[u] = f2u(o[u]);
  return *(uint4*)tmp;
}

// ---------------- dtype detection ----------------
__global__ void k_flag_init(int* flag){ if (threadIdx.x==0 && blockIdx.x==0) *flag = 0; }
__global__ void k_detect(const u16* __restrict__ p, int n, int* flag){
  int hit = 0;
  for (int i = blockIdx.x*blockDim.x + threadIdx.x; i < n; i += gridDim.x*blockDim.x){
    u16 u = p[i];
    if ((u & 0x7F80u) == 0x7F80u) hit = 1;
  }
  if (hit) atomicOr(flag, 1);
}

// ---------------- elementwise ----------------
__global__ void k_cvt_in(const void* __restrict__ s, float* __restrict__ d, int n,
                         const int* __restrict__ flag){
  int f = *flag;
  for (int i = blockIdx.x*blockDim.x + threadIdx.x; i < n; i += gridDim.x*blockDim.x)
    d[i] = ldd(s, i, 2, f);
}
__global__ void k_out_dual(const float* __restrict__ s, void* __restrict__ d, int n,
                           const int* __restrict__ flag){
  int f = *flag;
  for (int i = blockIdx.x*blockDim.x + threadIdx.x; i < n; i += gridDim.x*blockDim.x){
    if (f) ((float*)d)[i] = s[i];
    else   ((u16*)d)[i] = f2u(s[i]);
  }
}
// Y = P0+P1+P2+P3 (fp32, float4-vectorized)
__global__ void k_sum4(const float* __restrict__ P, size_t s, float* __restrict__ Y, int n4){
  for (int i = blockIdx.x*blockDim.x + threadIdx.x; i < n4; i += gridDim.x*blockDim.x){
    float4 a = ((const float4*)P)[i];
    float4 b = ((const float4*)(P + s))[i];
    float4 c = ((const float4*)(P + 2*s))[i];
    float4 d = ((const float4*)(P + 3*s))[i];
    float4 o; o.x=a.x+b.x+c.x+d.x; o.y=a.y+b.y+c.y+d.y;
    o.z=a.z+b.z+c.z+d.z; o.w=a.w+b.w+c.w+d.w;
    ((float4*)Y)[i] = o;
  }
}

// ---------------- weight composition: W' = A @ B (256x256 each), raw-dual A/B ----------------
struct CompW { const void* A[27]; size_t ao[27]; const void* B[27]; size_t bo[27]; u16* W[27]; };
__global__ __launch_bounds__(256) void k_compose_w(CompW cw, const int* __restrict__ flag){
  int f = *flag;
  int z = blockIdx.z;
  const void* A = cw.A[z]; size_t ao = cw.ao[z];
  const void* B = cw.B[z]; size_t bo = cw.bo[z];
  u16* Wo = cw.W[z];
  int ea = effdt(2,f), eb = ea;
  __shared__ __align__(16) u16 As[64*40];
  __shared__ __align__(16) u16 Bs[64*40];
  int bm = blockIdx.x*64, bn = blockIdx.y*64;
  int t = threadIdx.x;
  int lane = t & 63, wv = t >> 6;
  int wrow = (wv>>1)<<5, wcol = (wv&1)<<5;
  int quad = lane>>4, mr = lane&15;
  f32x4 a00 = {0.f,0.f,0.f,0.f}, a01 = a00, a10 = a00, a11 = a00;
  for (int k0 = 0; k0 < 256; k0 += 32){
    { int srow = t>>2, scg = (t&3)<<3;
      *(uint4*)&As[srow*40+scg] = ld8pack(A, ao + (size_t)(bm+srow)*256 + k0 + scg, ea); }
    { int kk = t>>3, c8 = (t&7)<<3;
      float o8[8]; ld8f(B, bo + (size_t)(k0+kk)*256 + bn + c8, eb, o8);
#pragma unroll
      for (int u = 0; u < 8; ++u) Bs[(c8+u)*40 + kk] = f2u(o8[u]); }
    __syncthreads();
    bf16x8 a0 = *(const bf16x8*)&As[(wrow+mr)*40+quad*8];
    bf16x8 a1 = *(const bf16x8*)&As[(wrow+16+mr)*40+quad*8];
    bf16x8 b0 = *(const bf16x8*)&Bs[(wcol+mr)*40+quad*8];
    bf16x8 b1 = *(const bf16x8*)&Bs[(wcol+16+mr)*40+quad*8];
    a00 = __builtin_amdgcn_mfma_f32_16x16x32_bf16(a0,b0,a00,0,0,0);
    a01 = __builtin_amdgcn_mfma_f32_16x16x32_bf16(a0,b1,a01,0,0,0);
    a10 = __builtin_amdgcn_mfma_f32_16x16x32_bf16(a1,b0,a10,0,0,0);
    a11 = __builtin_amdgcn_mfma_f32_16x16x32_bf16(a1,b1,a11,0,0,0);
    __syncthreads();
  }
  f32x4 av[4] = {a00,a01,a10,a11};
#pragma unroll
  for (int i = 0; i < 2; ++i)
#pragma unroll
  for (int j = 0; j < 2; ++j){
    f32x4 a = av[i*2+j];
    int col = bn + wcol + j*16 + mr;
#pragma unroll
    for (int r = 0; r < 4; ++r){
      int row = bm + wrow + i*16 + quad*4 + r;
      Wo[(size_t)row*256 + col] = f2u(a[r]);
    }
  }
}
struct CompB { const void* A[27]; size_t ao[27]; const void* b1[27]; size_t b1o[27];
               const void* b2[27]; size_t b2o[27]; u16* bo[27]; };
__global__ __launch_bounds__(256) void k_compose_b(CompB cb, const int* __restrict__ flag){
  int f = *flag;
  int z = blockIdx.x, o = threadIdx.x;
  float acc = 0.f;
  for (int j = 0; j < 256; ++j)
    acc += ldd(cb.A[z], cb.ao[z] + (size_t)o*256 + j, 2, f) * ldd(cb.b1[z], cb.b1o[z] + j, 2, f);
  cb.bo[z][o] = f2u(acc + ldd(cb.b2[z], cb.b2o[z] + o, 2, f));
}

// ---------------- generalized MFMA GEMM, BK=64, optional split-K ----------------
// Y[z*zstride + r*ldy + o] = act( sum_{k in chunk z} (X1+X2)[r,k] * Wsel[o,k] + bias(z==0) )
// W/bias set 2 for row-blocks with bm >= Rsplit. K and kchunk must be multiples of 64.
__global__ __launch_bounds__(256) void k_gemm(
    const void* __restrict__ X1, size_t xo1, int xt1,
    const void* __restrict__ X2, size_t xo2, int xt2,      // xt2 < 0 : none
    const void* __restrict__ W1, size_t wo1, int wt1,
    const void* __restrict__ B1v, size_t bo1, int bt1,
    const void* __restrict__ W2, size_t wo2, int wt2,
    const void* __restrict__ B2v, size_t bo2, int bt2,
    void* __restrict__ Y, int yt, int ldy, size_t zstride,
    int R, int K, int O, int Rsplit, int relu, int kchunk,
    const int* __restrict__ flag)
{
  __shared__ __align__(16) u16 As[64*72];
  __shared__ __align__(16) u16 Bs[64*72];
  int f = *flag;
  int bm = blockIdx.x*64, bn = blockIdx.y*64;
  int z = blockIdx.z;
  int kbeg = z * kchunk;
  int kend = kbeg + kchunk; if (kend > K) kend = K;
  bool second = (bm >= Rsplit);
  const void* W = second ? W2 : W1;  size_t wo = second ? wo2 : wo1;  int wt = second ? wt2 : wt1;
  const void* Bv = second ? B2v : B1v; size_t bo = second ? bo2 : bo1; int bt = second ? bt2 : bt1;
  int ex1 = effdt(xt1, f), ew = effdt(wt, f);
  int t = threadIdx.x;
  int srow = t >> 2, scg = (t & 3) << 3;
  int lane = t & 63, wv = t >> 6;
  int wrow = (wv >> 1) << 5, wcol = (wv & 1) << 5;
  int quad = lane >> 4, mr = lane & 15;
  f32x4 acc00 = {0.f,0.f,0.f,0.f}, acc01 = acc00, acc10 = acc00, acc11 = acc00;
  for (int k0 = kbeg; k0 < kend; k0 += 64) {
    { // stage X rows: cols [k0, k0+64)
      int gr = bm + srow;
      uint4 v0 = {0u,0u,0u,0u}, v1 = v0;
      if (gr < R) {
        size_t e = xo1 + (size_t)gr*K + k0 + scg;
        if (xt2 < 0) {
          v0 = ld8pack(X1, e, ex1);
          v1 = ld8pack(X1, e + 32, ex1);
        } else {
          int ex2 = effdt(xt2, f);
          size_t e2 = xo2 + (size_t)gr*K + k0 + scg;
          float a8[8], b8[8]; u16 tmp[8];
          ld8f(X1, e, ex1, a8); ld8f(X2, e2, ex2, b8);
#pragma unroll
          for (int u = 0; u < 8; ++u) tmp[u] = f2u(a8[u] + b8[u]);
          v0 = *(uint4*)tmp;
          ld8f(X1, e + 32, ex1, a8); ld8f(X2, e2 + 32, ex2, b8);
#pragma unroll
          for (int u = 0; u < 8; ++u) tmp[u] = f2u(a8[u] + b8[u]);
          v1 = *(uint4*)tmp;
        }
      }
      *(uint4*)&As[srow*72 + scg]      = v0;
      *(uint4*)&As[srow*72 + 32 + scg] = v1;
    }
    { // stage W rows (output cols)
      int go = bn + srow;
      uint4 v0 = {0u,0u,0u,0u}, v1 = v0;
      if (go < O) {
        size_t e = wo + (size_t)go*K + k0 + scg;
        v0 = ld8pack(W, e, ew);
        v1 = ld8pack(W, e + 32, ew);
      }
      *(uint4*)&Bs[srow*72 + scg]      = v0;
      *(uint4*)&Bs[srow*72 + 32 + scg] = v1;
    }
    __syncthreads();
#pragma unroll
    for (int ks = 0; ks < 2; ++ks) {
      int kb = ks*32 + quad*8;
      bf16x8 a0 = *(const bf16x8*)&As[(wrow      + mr)*72 + kb];
      bf16x8 a1 = *(const bf16x8*)&As[(wrow + 16 + mr)*72 + kb];
      bf16x8 b0 = *(const bf16x8*)&Bs[(wcol      + mr)*72 + kb];
      bf16x8 b1 = *(const bf16x8*)&Bs[(wcol + 16 + mr)*72 + kb];
      acc00 = __builtin_amdgcn_mfma_f32_16x16x32_bf16(a0, b0, acc00, 0, 0, 0);
      acc01 = __builtin_amdgcn_mfma_f32_16x16x32_bf16(a0, b1, acc01, 0, 0, 0);
      acc10 = __builtin_amdgcn_mfma_f32_16x16x32_bf16(a1, b0, acc10, 0, 0, 0);
      acc11 = __builtin_amdgcn_mfma_f32_16x16x32_bf16(a1, b1, acc11, 0, 0, 0);
    }
    __syncthreads();
  }
  float* Yf = (float*)Y + z*zstride;
  u16*   Yu = (u16*)Y + z*zstride;
  f32x4 av[4] = {acc00, acc01, acc10, acc11};
#pragma unroll
  for (int i = 0; i < 2; ++i)
#pragma unroll
  for (int j = 0; j < 2; ++j) {
    f32x4 a = av[i*2 + j];
    int col = bn + wcol + j*16 + mr;
    if (col >= O) continue;
    float bv = (z == 0) ? ldd(Bv, bo + col, bt, f) : 0.f;
#pragma unroll
    for (int r = 0; r < 4; ++r) {
      int row = bm + wrow + i*16 + quad*4 + r;
      if (row >= R) continue;
      float v = a[r] + bv;
      if (relu) v = fmaxf(v, 0.f);
      if (yt == 0) Yf[(size_t)row*ldy + col] = v;
      else         Yu[(size_t)row*ldy + col] = f2u(v);
    }
  }
}

// ---------------- LayerNorm (single + pair) ----------------
__device__ __forceinline__ float blk_sum256(float v, float* red){
  for (int off = 32; off; off >>= 1) v += __shfl_down(v, off, 64);
  int lane = threadIdx.x & 63, w = threadIdx.x >> 6;
  if (lane == 0) red[w] = v;
  __syncthreads();
  v = red[0] + red[1] + red[2] + red[3];
  __syncthreads();
  return v;
}
__device__ __forceinline__ float ln_one(float x, size_t go, size_t bo,
    const void* gb, const void* bb, int f, float* red, int i){
  float m = blk_sum256(x, red) * (1.0f/256.0f);
  float d0 = x - m;
  float var = blk_sum256(d0*d0, red) * (1.0f/256.0f);
  float r = rsqrtf(var + 1e-5f);
  return d0 * r * ldd(gb, go + i, 2, f) + ldd(bb, bo + i, 2, f);
}
__global__ __launch_bounds__(256) void k_ln(
    const float* __restrict__ A, const float* __restrict__ Bp, const float* __restrict__ Cp,
    const void* __restrict__ gb, const void* __restrict__ bb, size_t o1,
    float* __restrict__ Y, const int* __restrict__ flag)
{
  __shared__ float red[4];
  int f = *flag;
  int row = blockIdx.x, i = threadIdx.x;
  size_t idx = (size_t)row*256 + i;
  float x = A[idx];
  if (Bp) x += Bp[idx];
  if (Cp) x += Cp[idx];
  Y[idx] = ln_one(x, o1, o1, gb, bb, f, red, i);
}
__global__ __launch_bounds__(256) void k_ln_pair(
    const float* __restrict__ A1, const float* __restrict__ B1, const float* __restrict__ C1,
    size_t o1, float* __restrict__ Y1,
    const float* __restrict__ A2, const float* __restrict__ B2,
    size_t o2, float* __restrict__ Y2,
    const void* __restrict__ gb, const void* __restrict__ bb, const int* __restrict__ flag)
{
  __shared__ float red[4];
  int f = *flag;
  int row = blockIdx.x, i = threadIdx.x;
  size_t idx = (size_t)row*256 + i;
  float x1 = A1[idx] + B1[idx];
  if (C1) x1 += C1[idx];
  float x2 = A2[idx] + B2[idx];
  float y1 = ln_one(x1, o1, o1, gb, bb, f, red, i);
  float y2 = ln_one(x2, o2, o2, gb, bb, f, red, i);
  Y1[idx] = y1;
  Y2[idx] = y2;
}

// ---------------- flash attention pair (z selects problem) ----------------
struct FP {
  const u16* Q[2]; int qs[2];
  const u16* K[2]; int ks[2];
  const u16* V[2]; int vs[2];
  u16* O[2];
};
__global__ __launch_bounds__(256) void k_flash_pair(FP fp, int NQr, int Nk, float scale)
{
  __shared__ __align__(16) u16 Qs[64*40];
  __shared__ __align__(16) u16 Ks[64*40];
  __shared__ __align__(16) u16 Vs[32*72];
  __shared__ __align__(16) u16 Ps[64*72];
  int z = blockIdx.z;
  const u16* Q = fp.Q[z]; int qstr = fp.qs[z];
  const u16* K = fp.K[z]; int kstr = fp.ks[z];
  const u16* V = fp.V[z]; int vstr = fp.vs[z];
  u16* O = fp.O[z];
  int t = threadIdx.x;
  int b = blockIdx.y >> 3, h = blockIdx.y & 7;
  int q0 = blockIdx.x * 64;
  int lane = t & 63, wv = t >> 6;
  int quad = lane >> 4, mr = lane & 15;
  {
    int qi = t >> 2, c8 = (t & 3) * 8;
    int qg = q0 + qi; if (qg >= NQr) qg = NQr - 1;
    *(uint4*)&Qs[qi*40 + c8] = *(const uint4*)(Q + ((size_t)qg*8 + b)*qstr + h*32 + c8);
  }
  f32x4 o0 = {0.f,0.f,0.f,0.f}, o1 = o0;
  float m_run[4], l_run[4];
#pragma unroll
  for (int r = 0; r < 4; ++r){ m_run[r] = -1e30f; l_run[r] = 0.f; }
  __syncthreads();

  for (int k0 = 0; k0 < Nk; k0 += 64) {
    {
      int ki = t >> 2, c8 = (t & 3)*8;
      int kg = k0 + ki;
      uint4 kv = {0u,0u,0u,0u}, vv = {0u,0u,0u,0u};
      if (kg < Nk) {
        kv = *(const uint4*)(K + ((size_t)kg*8 + b)*kstr + h*32 + c8);
        vv = *(const uint4*)(V + ((size_t)kg*8 + b)*vstr + h*32 + c8);
      }
      *(uint4*)&Ks[ki*40 + c8] = kv;
      u16 tmp[8]; *(uint4*)tmp = vv;
#pragma unroll
      for (int u = 0; u < 8; ++u) Vs[(c8+u)*72 + ki] = tmp[u];
    }
    __syncthreads();
    bf16x8 aq = *(const bf16x8*)&Qs[(wv*16 + mr)*40 + quad*8];
    f32x4 s[4];
#pragma unroll
    for (int j = 0; j < 4; ++j) {
      bf16x8 bk = *(const bf16x8*)&Ks[(j*16 + mr)*40 + quad*8];
      f32x4 zz = {0.f,0.f,0.f,0.f};
      s[j] = __builtin_amdgcn_mfma_f32_16x16x32_bf16(aq, bk, zz, 0, 0, 0);
      s[j] *= scale;
    }
    float alpha[4];
#pragma unroll
    for (int r = 0; r < 4; ++r) {
      float cm = -1e30f;
#pragma unroll
      for (int j = 0; j < 4; ++j) {
        int kg = k0 + j*16 + mr;
        cm = fmaxf(cm, (kg < Nk) ? s[j][r] : -1e30f);
      }
      for (int msk = 1; msk < 16; msk <<= 1)
        cm = fmaxf(cm, __shfl_xor(cm, msk, 64));
      float mn = fmaxf(m_run[r], cm);
      alpha[r] = __expf(m_run[r] - mn);
      m_run[r] = mn;
      float rsum = 0.f;
#pragma unroll
      for (int j = 0; j < 4; ++j) {
        int kg = k0 + j*16 + mr;
        float p = (kg < Nk) ? __expf(s[j][r] - mn) : 0.f;
        s[j][r] = p;
        rsum += p;
      }
      for (int msk = 1; msk < 16; msk <<= 1)
        rsum += __shfl_xor(rsum, msk, 64);
      l_run[r] = l_run[r]*alpha[r] + rsum;
    }
#pragma unroll
    for (int j = 0; j < 4; ++j)
#pragma unroll
      for (int r = 0; r < 4; ++r)
        Ps[(wv*16 + quad*4 + r)*72 + j*16 + mr] = f2u(s[j][r]);
    __syncthreads();
    f32x4 pv0 = {0.f,0.f,0.f,0.f}, pv1 = pv0;
#pragma unroll
    for (int st = 0; st < 2; ++st) {
      bf16x8 ap  = *(const bf16x8*)&Ps[(wv*16 + mr)*72 + st*32 + quad*8];
      bf16x8 bv0 = *(const bf16x8*)&Vs[(mr)*72      + st*32 + quad*8];
      bf16x8 bv1 = *(const bf16x8*)&Vs[(16 + mr)*72 + st*32 + quad*8];
      pv0 = __builtin_amdgcn_mfma_f32_16x16x32_bf16(ap, bv0, pv0, 0, 0, 0);
      pv1 = __builtin_amdgcn_mfma_f32_16x16x32_bf16(ap, bv1, pv1, 0, 0, 0);
    }
#pragma unroll
    for (int r = 0; r < 4; ++r) {
      o0[r] = o0[r]*alpha[r] + pv0[r];
      o1[r] = o1[r]*alpha[r] + pv1[r];
    }
    __syncthreads();
  }
#pragma unroll
  for (int r = 0; r < 4; ++r) {
    int qg = q0 + wv*16 + quad*4 + r;
    if (qg >= NQr) continue;
    float inv = 1.0f / l_run[r];
    u16* dst = O + ((size_t)qg*8 + b)*256 + h*32;
    dst[mr]      = f2u(o0[r]*inv);
    dst[16 + mr] = f2u(o1[r]*inv);
  }
}

// ---------------- fused box-MLP + rbs update + sine4 ----------------
__global__ __launch_bounds__(256) void k_boxsine(
    const void* __restrict__ box, const void* __restrict__ w1, size_t w1o,
    const void* __restrict__ b1v, size_t b1o,
    const void* __restrict__ w2, size_t w2o, const void* __restrict__ b2v, size_t b2o,
    float* __restrict__ RBS, const u16* __restrict__ pt, u16* __restrict__ qse,
    const int* __restrict__ flag)
{
  int f = *flag;
  int row = blockIdx.x, t = threadIdx.x;
  __shared__ float xs[4];
  __shared__ float hs[128];
  __shared__ float rb[4];
  if (t < 4) xs[t] = ldd(box, (size_t)row*4 + t, 2, f);
  __syncthreads();
  if (t < 128) {
    float acc = ldd(b1v, b1o + t, 2, f);
#pragma unroll
    for (int j = 0; j < 4; ++j) acc += ldd(w1, w1o + (size_t)t*4 + j, 2, f) * xs[j];
    hs[t] = fmaxf(acc, 0.f);
  }
  __syncthreads();
  if (t < 4) {
    float acc = ldd(b2v, b2o + t, 2, f);
    for (int j = 0; j < 128; ++j) acc += ldd(w2, w2o + (size_t)t*128 + j, 2, f) * hs[j];
    float nr = RBS[(size_t)row*4 + t] + acc;
    RBS[(size_t)row*4 + t] = nr;
    rb[t] = nr;
  }
  __syncthreads();
  int c = t >> 6, i = t & 63;
  float x = 1.f/(1.f + __expf(-rb[0]));
  float y = 1.f/(1.f + __expf(-rb[1]));
  int j = i >> 1;
  float dt = powf(10000.f, (float)(2*j)/64.f);
  const float s2pi = 6.283185307179586f;
  float base = (c == 0 || c == 3) ? y : x;
  float a = base * s2pi / dt;
  bool even = ((i & 1) == 0);
  float p1 = even ? sinf(a) : cosf(a);
  float v = (c <= 1) ? p1 : (even ? sinf(p1) : cosf(p1));
  if (pt) v *= u2f(pt[(size_t)row*256 + t]);
  qse[(size_t)row*256 + t] = f2u(v);
}

// ---------------- host ----------------
extern "C" void kernel_launch(void* const* d_in, const int* in_sizes, int n_in,
                              void* d_out, int out_size, void* d_ws, size_t ws_size,
                              hipStream_t stream) {
  (void)in_sizes; (void)n_in; (void)out_size; (void)ws_size;

  int* FLAG = (int*)d_ws;
  float* f32p = (float*)((char*)d_ws + 16);
  size_t fo = 0;
  auto AF = [&](size_t n){ float* p = f32p + fo; fo += n; return p; };
  float* OUT = AF(614400);
  float* T   = AF((size_t)RPAD*256);
  float* TP  = AF((size_t)RPAD*256);
  float* T2  = AF(614400);             // T2P must follow immediately
  float* T2P = AF(614400);
  float* Q1  = AF((size_t)2*RPAD*256); // stacked FFN2 output
  float* PART= AF((size_t)4*2*RPAD*256); // split-K partials (4 chunks)
  float* RBS = AF(9600);
  u16* u16p = (u16*)(f32p + fo);
  size_t uo = 0;
  auto AU = [&](size_t n){ u16* p = u16p + uo; uo += (n + 7) & ~(size_t)7; return p; };
  u16* QSE  = AU(614400);
  u16* QC   = AU(614400);
  u16* AO   = AU(2*614400);            // [content ; pos]
  u16* PT   = AU(614400);
  u16* QB   = AU(2*614400);            // [Q_content ; Q_pos]
  u16* QKB  = AU(1228800);             // SA [q|k], row stride 512
  u16* KVV  = AU((size_t)RM*768);      // [K_c|V_c|V_p], stride 768   (HID aliases)
  u16* KPOS = AU((size_t)RM*256);      // K_pos / SA V
  u16* KSPARE = AU((size_t)RM*256);    // extends HID span
  u16* HID  = KVV;                     // 4864*2048 = 9,961,472 <= 10,485,760
  u16* SAV  = KPOS;
  u16* QPW  = AU(6*65536);  u16* QPB  = AU(6*256);
  u16* KVVW = AU(5*196608); u16* KVVB = AU(5*768);
  u16* KPW  = AU(5*65536);  u16* KPB  = AU(5*256);
  u16* VP0W = AU(65536);    u16* VP0B = AU(256);
  (void)KSPARE;

  k_flag_init<<<1,64,0,stream>>>(FLAG);
  k_detect<<<256,256,0,stream>>>((const u16*)d_in[1], 262144, FLAG);
  k_cvt_in<<<600,256,0,stream>>>(d_in[0], OUT, RQ*EEe, FLAG);

  // ---- weight compositions ----
  {
    CompW cw; CompB cb; int nz = 0;
    auto addc = [&](int ia, size_t ao, int ib, size_t bo_, u16* W,
                    int ib1, size_t b1o, int ib2, size_t b2o, u16* bo){
      cw.A[nz]=d_in[ia]; cw.ao[nz]=ao; cw.B[nz]=d_in[ib]; cw.bo[nz]=bo_; cw.W[nz]=W;
      cb.A[nz]=d_in[ia]; cb.ao[nz]=ao; cb.b1[nz]=d_in[ib1]; cb.b1o[nz]=b1o;
      cb.b2[nz]=d_in[ib2]; cb.b2o[nz]=b2o; cb.bo[nz]=bo; ++nz;
    };
    for (int l = 0; l < 6; ++l)
      addc(9,(size_t)l*196608, 21,(size_t)l*65536, QPW+(size_t)l*65536,
           22,(size_t)l*256, 10,(size_t)l*768, QPB+(size_t)l*256);
    for (int l = 1; l < 6; ++l) {
      size_t wk = (size_t)l*196608 + 65536, wv = (size_t)l*196608 + 131072;
      u16* WS = KVVW + (size_t)(l-1)*196608;
      u16* BS = KVVB + (size_t)(l-1)*768;
      addc(9,wk, 19,(size_t)l*65536, WS,        20,(size_t)l*256, 10,(size_t)l*768+256, BS);
      addc(9,wv, 17,(size_t)l*65536, WS+65536,  18,(size_t)l*256, 10,(size_t)l*768+512, BS+256);
      addc(9,wv, 23,(size_t)l*65536, WS+131072, 24,(size_t)l*256, 10,(size_t)l*768+512, BS+512);
      addc(9,wk, 15,(size_t)l*65536, KPW+(size_t)(l-1)*65536,
           16,(size_t)l*256, 10,(size_t)l*768+256, KPB+(size_t)(l-1)*256);
    }
    addc(9,131072, 23,0, VP0W, 24,0, 10,512, VP0B);
    k_compose_w<<<dim3(4,4,27),256,0,stream>>>(cw, FLAG);
    k_compose_b<<<27,256,0,stream>>>(cb, FLAG);
  }

  struct P { const void* p; size_t o; int t; };
  auto GEMM = [&](P X1, P X2, P W1, P B1, P W2, P B2, void* Y, int yt, int ldy,
                  int R, int K, int O, int Rsplit, int relu, int kc, int gz, size_t zs){
    dim3 g((R+63)/64, (O+63)/64, gz);
    k_gemm<<<g,256,0,stream>>>(X1.p,X1.o,X1.t, X2.p,X2.o,X2.t, W1.p,W1.o,W1.t,
                               B1.p,B1.o,B1.t, W2.p,W2.o,W2.t, B2.p,B2.o,B2.t,
                               Y,yt,ldy,zs,R,K,O,Rsplit,relu,kc,FLAG);
  };
  P NONE = {nullptr, 0, -1};
  auto RAW = [&](int i, size_t o){ P p = {d_in[i], o, 2}; return p; };
  auto WS1 = [&](const u16* q){ P p = {q, 0, 1}; return p; };
  auto WS0 = [&](const float* q){ P p = {q, 0, 0}; return p; };
  auto G1 = [&](P X, P W, P B, void* Y, int yt, int ldy, int R, int K, int O, int relu){
    GEMM(X, NONE, W, B, W, B, Y, yt, ldy, R, K, O, R+64, relu, K, 1, 0);
  };
  auto G2 = [&](P X, P X2, P W, P B, void* Y, int yt, int ldy, int R, int K, int O){
    GEMM(X, X2, W, B, W, B, Y, yt, ldy, R, K, O, R+64, 0, K, 1, 0);
  };
  auto LN1k = [&](const float* A, const float* Bp, const float* Cp, int l, int j, float* Y){
    size_t o1 = ((size_t)l*6 + j)*EEe;
    k_ln<<<RQ,256,0,stream>>>(A,Bp,Cp, d_in[33], d_in[34], o1, Y, FLAG);
  };
  const float rs = 0.17677669529663687f;  // 1/sqrt(32)

  // rbs = lin(relu(lin(query_pos, rh1)), rh2)
  G1(RAW(3,0), RAW(39,0), RAW(40,0), QC, 1, 256, RQ, 256, 256, 1);
  G1(WS1(QC),  RAW(41,0), RAW(42,0), RBS, 0, 4,  RQ, 256, 4,   0);

  for (int l = 0; l < LLl; ++l) {
    size_t sw = (size_t)l*196608, sb = (size_t)l*768;
    if (l > 0) {
      G1(WS0(OUT), RAW(35,0), RAW(36,0), QC, 1, 256, RQ, 256, 256, 1);
      G1(WS1(QC),  RAW(37,0), RAW(38,0), PT, 1, 256, RQ, 256, 256, 0);
    }
    k_boxsine<<<RQ,256,0,stream>>>(d_in[4], d_in[43],(size_t)l*512, d_in[44],(size_t)l*128,
                                   d_in[45],(size_t)l*512, d_in[46],(size_t)l*4,
                                   RBS, l > 0 ? PT : (const u16*)nullptr, QSE, FLAG);

    // ---- self-attention: [q|k] from OUT+qpos (fused add), v from OUT ----
    G2(WS0(OUT), RAW(3,0), RAW(5,sw), RAW(6,sb), QKB, 1, 512, RQ, 256, 512);
    G1(WS0(OUT), RAW(5,sw+131072), RAW(6,sb+512), SAV, 1, 256, RQ, 256, 256, 0);
    {
      FP fp = {};
      fp.Q[0]=QKB; fp.qs[0]=512; fp.K[0]=QKB+256; fp.ks[0]=512;
      fp.V[0]=SAV; fp.vs[0]=256; fp.O[0]=AO;
      k_flash_pair<<<dim3(5,64,1),256,0,stream>>>(fp, NQq, NQq, rs);
    }
    G1(WS1(AO), RAW(7,(size_t)l*65536), RAW(8,(size_t)l*256), Q1, 0, 256, RQ, 256, 256, 0);
    LN1k(OUT, Q1, nullptr, l, 0, T);

    // ---- cross-attention K/V ----
    if (l == 0) {
      G2(RAW(1,0), RAW(2,0), RAW(9,sw+65536), RAW(10,sb+256), KVV, 1, 768, RM, 256, 256);
      G1(RAW(1,0), RAW(9,sw+131072), RAW(10,sb+512), KVV+256, 1, 768, RM, 256, 256, 0);
      G1(RAW(1,0), WS1(VP0W), WS1(VP0B), KVV+512, 1, 768, RM, 256, 256, 0);
      G1(RAW(2,0), RAW(9,sw+65536), RAW(10,sb+256), KPOS, 1, 256, RM, 256, 256, 0);
    } else {
      G1(RAW(1,0), WS1(KVVW+(size_t)(l-1)*196608), WS1(KVVB+(size_t)(l-1)*768),
         KVV, 1, 768, RM, 256, 768, 0);
      G1(RAW(2,0), WS1(KPW+(size_t)(l-1)*65536), WS1(KPB+(size_t)(l-1)*256),
         KPOS, 1, 256, RM, 256, 256, 0);
    }

    // ---- Q projections ----
    if (l == 0) {
      G1(RAW(3,0), RAW(13,0), RAW(14,0), Q1, 0, 256, RQ, 256, 256, 0);
      G2(WS0(T), WS0(Q1), RAW(9,sw), RAW(10,sb), QB, 1, 256, RQ, 256, 256);
    } else {
      G1(WS0(T), RAW(9,sw), RAW(10,sb), QB, 1, 256, RQ, 256, 256, 0);
    }
    G1(WS1(QSE), WS1(QPW+(size_t)l*65536), WS1(QPB+(size_t)l*256),
       QB+614400, 1, 256, RQ, 256, 256, 0);

    // ---- content + positional flash, one launch ----
    {
      FP fp = {};
      fp.Q[0]=QB;        fp.qs[0]=256; fp.K[0]=KVV;     fp.ks[0]=768;
      fp.V[0]=KVV+256;   fp.vs[0]=768; fp.O[0]=AO;
      fp.Q[1]=QB+614400; fp.qs[1]=256; fp.K[1]=KPOS;    fp.ks[1]=256;
      fp.V[1]=KVV+512;   fp.vs[1]=768; fp.O[1]=AO+614400;
      k_flash_pair<<<dim3(5,64,2),256,0,stream>>>(fp, NQq, MMm, rs);
    }
    G1(WS1(AO), RAW(11,(size_t)l*65536), RAW(12,(size_t)l*256),
       T2, 0, 256, 2*RQ, 256, 256, 0);

    // ---- LN pair #1: T=LN(T+T2+T2P,n1); TP=LN(T+T2P,n3) ----
    k_ln_pair<<<RQ,256,0,stream>>>(T, T2, T2P, ((size_t)l*6+1)*EEe, T,
                                   T, T2P, ((size_t)l*6+3)*EEe, TP,
                                   d_in[33], d_in[34], FLAG);

    // ---- merged FFN1 (rows < RPAD: lin*, rows >= RPAD: lp*) ----
    GEMM(WS0(T), NONE, RAW(25,(size_t)l*524288), RAW(26,(size_t)l*2048),
         RAW(29,(size_t)l*524288), RAW(30,(size_t)l*2048),
         HID, 1, 2048, 2*RPAD, 256, 2048, RPAD, 1, 256, 1, 0);
    // ---- merged FFN2, split-K x4 (K=2048, chunks of 512) -> partials -> Q1 ----
    GEMM(WS1(HID), NONE, RAW(27,(size_t)l*524288), RAW(28,(size_t)l*256),
         RAW(31,(size_t)l*524288), RAW(32,(size_t)l*256),
         PART, 0, 256, 2*RPAD, 2048, 256, RPAD, 0, 512, 4, (size_t)2*RPAD*256);
    k_sum4<<<1216,256,0,stream>>>(PART, (size_t)2*RPAD*256, Q1, (2*RPAD*256)/4);

    // ---- LN pair #2: T=LN(T+Q1a,n2); TP=LN(TP+Q1b,n4) ----
    k_ln_pair<<<RQ,256,0,stream>>>(T, Q1, nullptr, ((size_t)l*6+2)*EEe, T,
                                   TP, Q1 + (size_t)RPAD*256, ((size_t)l*6+4)*EEe, TP,
                                   d_in[33], d_in[34], FLAG);

    // ---- out = LN(t + tp) ----
    LN1k(T, TP, nullptr, l, 5, OUT);
  }

  k_out_dual<<<600,256,0,stream>>>(OUT, d_out, RQ*EEe, FLAG);
}